// Round 2
// baseline (153.959 us; speedup 1.0000x reference)
//
#include <hip/hip_runtime.h>
#include <math.h>

#define NB 16
#define NCTX 2048
#define NTEST 1024
#define NCTX_TOT (NB*NCTX)      /* 32768 */
#define NTEST_TOT (NB*NTEST)    /* 16384 */
#define NTOT (NCTX_TOT + NTEST_TOT) /* 49152 */

typedef _Float16 half8 __attribute__((ext_vector_type(8)));
typedef _Float16 half4 __attribute__((ext_vector_type(4)));
typedef _Float16 half2v __attribute__((ext_vector_type(2)));
typedef float f32x4 __attribute__((ext_vector_type(4)));

__device__ __forceinline__ float gelu_f(float x) {
  float x3 = x * x * x;
  float y = 0.7978845608028654f * fmaf(0.044715f, x3, x);
  float e = __expf(2.0f * y);
  float th = 1.0f - 2.0f * __builtin_amdgcn_rcpf(e + 1.0f);
  return 0.5f * x * (1.0f + th);
}

__device__ __forceinline__ float4 ldg4(const float* p) {
  return *reinterpret_cast<const float4*>(p);
}

__device__ __forceinline__ unsigned fkey(float f) {
  unsigned u = __float_as_uint(f);
  return (u & 0x80000000u) ? ~u : (u ^ 0x80000000u);
}
__device__ __forceinline__ float unfkey(unsigned k) {
  return (k & 0x80000000u) ? __uint_as_float(k ^ 0x80000000u)
                           : __uint_as_float(~k);
}

// ---------------------------------------------------------------------------
// Weight prep: fragment-contiguous fp16 packs (W2,W3,Wg + H1,H2) + ctype.
// Pack recipe (proven R10): P[((j*KS+ks)*64+l)*8+e] = fp16(W[(ks*32+(l>>4)*8+e)*N + 16j+(l&15)])
// ---------------------------------------------------------------------------
__global__ __launch_bounds__(256) void prep_kernel(
    const float* __restrict__ W1, const float* __restrict__ b1,
    const float* __restrict__ emb,
    const float* __restrict__ W2, const float* __restrict__ W3,
    const float* __restrict__ Wg,
    const float* __restrict__ H1, const float* __restrict__ H2,
    _Float16* __restrict__ W2P, _Float16* __restrict__ W3P,
    _Float16* __restrict__ WgP,
    _Float16* __restrict__ H1P, _Float16* __restrict__ H2P,
    float* __restrict__ ctype)
{
  int t = blockIdx.x * 256 + threadIdx.x;   // grid 16*256 = 4096
  { // W2: 8 j x 8 ks (N=128, K=256)
    int j = t >> 9, ks = (t >> 6) & 7, l = t & 63;
    int col = 16*j + (l & 15);
    int k0  = ks*32 + (l >> 4)*8;
    half8 o;
    #pragma unroll
    for (int e = 0; e < 8; ++e) o[e] = (_Float16)W2[(k0 + e)*128 + col];
    *reinterpret_cast<half8*>(&W2P[(size_t)t*8]) = o;
  }
  if (t < 1024) { // W3: 4 j x 4 ks (N=64, K=128)
    int j = t >> 8, ks = (t >> 6) & 3, l = t & 63;
    int col = 16*j + (l & 15);
    int k0  = ks*32 + (l >> 4)*8;
    half8 o;
    #pragma unroll
    for (int e = 0; e < 8; ++e) o[e] = (_Float16)W3[(k0 + e)*64 + col];
    *reinterpret_cast<half8*>(&W3P[(size_t)t*8]) = o;
  }
  if (t < 512) { // Wg: 4 j x 2 ks (N=64, K=64)
    int j = t >> 7, ks = (t >> 6) & 1, l = t & 63;
    int col = 16*j + (l & 15);
    int k0  = ks*32 + (l >> 4)*8;
    half8 o;
    #pragma unroll
    for (int e = 0; e < 8; ++e) o[e] = (_Float16)Wg[(k0 + e)*64 + col];
    *reinterpret_cast<half8*>(&WgP[(size_t)t*8]) = o;
  }
  if (t < 2048) { // H1: 16 j x 2 ks (N=256, K=64)
    int j = t >> 7, ks = (t >> 6) & 1, l = t & 63;
    int col = 16*j + (l & 15);
    int k0  = ks*32 + (l >> 4)*8;
    half8 o;
    #pragma unroll
    for (int e = 0; e < 8; ++e) o[e] = (_Float16)H1[(k0 + e)*256 + col];
    *reinterpret_cast<half8*>(&H1P[(size_t)t*8]) = o;
  }
  if (t < 2048) { // H2: 4 j x 8 ks (N=64, K=256)
    int j = t >> 9, ks = (t >> 6) & 7, l = t & 63;
    int col = 16*j + (l & 15);
    int k0  = ks*32 + (l >> 4)*8;
    half8 o;
    #pragma unroll
    for (int e = 0; e < 8; ++e) o[e] = (_Float16)H2[(k0 + e)*64 + col];
    *reinterpret_cast<half8*>(&H2P[(size_t)t*8]) = o;
  }
  if (t < 512) {
    int ty = t >> 8, c = t & 255;
    float acc = b1[c];
    #pragma unroll
    for (int k = 0; k < 4; ++k) acc = fmaf(emb[ty*4 + k], W1[k*256 + c], acc);
    ctype[t] = acc;
  }
}

// ---------------------------------------------------------------------------
// Fused front kernel v2: knn (16/19) + node_mlp (3/19), re-fused for
// co-scheduling, with LDS union shrunk to 20480 B -> 8 blocks/CU = 32
// waves/CU (was 34816 -> 4 blocks -> 16 waves). mlp role K-halves the
// h1 staging ([16][136] x 2 phases, identical accumulation order).
// knn role: packed (key<<32|idx) u64 select -> exact lexicographic rank,
// unrolled 32-compare fast path kills the serial runtime rank loop.
// ---------------------------------------------------------------------------
__global__ __launch_bounds__(256, 8) void front_kernel(
    const float* __restrict__ s_ctx, const float* __restrict__ f_ctx,
    const float* __restrict__ s_test, int* __restrict__ senders,
    const float* __restrict__ ctype, const float* __restrict__ W1,
    const _Float16* __restrict__ W2P, const float* __restrict__ b2,
    const _Float16* __restrict__ W3P, const float* __restrict__ b3,
    const float* __restrict__ ln_g, const float* __restrict__ ln_b,
    const _Float16* __restrict__ WgP,
    const float* __restrict__ a_src, const float* __restrict__ a_dst,
    float* __restrict__ nodes, _Float16* __restrict__ xph,
    float* __restrict__ xps, float* __restrict__ xpd)
{
  __shared__ __align__(16) char smem[20480];   // union: knn 20480 / mlp 4*5120
  const int t    = threadIdx.x;
  const int lane = t & 63;
  const int w    = t >> 6;
  const int blk  = blockIdx.x;        // 4864 = 256 groups * (16 knn + 3 mlp)
  const int grp  = blk / 19;
  const int rr_  = blk % 19;

  if (rr_ < 16) {
    // ---------------- KNN role (id 0..4095) -------------------------------
    const int id = grp*16 + rr_;
    float2* xy = reinterpret_cast<float2*>(smem);                     // 16384B
    unsigned long long (*sk)[128] =
        reinterpret_cast<unsigned long long(*)[128]>(smem + 16384);   // 4096B
    const int bb = id >> 8;
    const int q  = (id & 255) * 4 + w;

    const float* cb = s_ctx + (size_t)bb * NCTX * 2;
    for (int i = t; i < NCTX; i += 256)
      xy[i] = make_float2(cb[2*i], cb[2*i+1]);
    __syncthreads();

    const int trow = bb * NTEST + q;
    const float qx = s_test[(size_t)trow*2];
    const float qy = s_test[(size_t)trow*2 + 1];
    const float qq = __fadd_rn(__fmul_rn(qx,qx), __fmul_rn(qy,qy));

    float d[32];
    float mn = 3.4e38f;
    #pragma unroll
    for (int it = 0; it < 32; ++it) {
      float2 p = xy[it*64 + lane];
      float ss  = __fadd_rn(__fmul_rn(p.x,p.x), __fmul_rn(p.y,p.y));
      float dot = __fadd_rn(__fmul_rn(qx, p.x), __fmul_rn(qy, p.y));
      float d2  = __fsub_rn(__fadd_rn(qq, ss), __fmul_rn(2.0f, dot));
      d[it] = d2;
      mn = fminf(mn, d2);
    }

    unsigned key = fkey(mn);
    unsigned acc = 0u;
    #pragma unroll
    for (int bit = 31; bit >= 0; --bit) {
      unsigned candv = acc | (1u << bit);
      unsigned long long bal = __ballot(key < candv);
      if (__popcll(bal) < 16) acc = candv;
    }
    const float Tf = unfkey(acc);

    int base = 0;
    #pragma unroll
    for (int it = 0; it < 32; ++it) {
      bool pr = (d[it] <= Tf);
      unsigned long long m = __ballot(pr);
      if (pr) {
        int pos = base + __popcll(m & ((1ULL << lane) - 1ULL));
        if (pos < 128)
          sk[w][pos] = ((unsigned long long)fkey(d[it]) << 32)
                     | (unsigned)(it*64 + lane);       // idx in [0,2047]
      }
      base += __popcll(m);
    }
    const int S = base;                   // uniform; S >= 16 guaranteed

    if (S <= 32) {
      // pad remaining slots so the unrolled compare is safe
      if (lane >= S && lane < 32) sk[w][lane] = ~0ULL;
      unsigned long long pm = sk[w][lane & 31];
      int r0 = 0;
      #pragma unroll
      for (int j = 0; j < 32; ++j)
        r0 += (int)(sk[w][j] < pm);       // (key,idx) lexicographic rank
      if (lane < S && r0 < 16)
        senders[(size_t)trow*16 + r0] = bb*NCTX + (int)(pm & 0xFFFFFFFFu);
    } else if (S <= 128) {
      unsigned long long p0 = (lane      < S) ? sk[w][lane]      : ~0ULL;
      unsigned long long p1 = (lane + 64 < S) ? sk[w][lane + 64] : ~0ULL;
      int r0 = 0, r1 = 0;
      for (int j = 0; j < S; ++j) {       // broadcast LDS reads
        unsigned long long kj = sk[w][j];
        r0 += (int)(kj < p0);
        r1 += (int)(kj < p1);
      }
      if (lane < S && r0 < 16)
        senders[(size_t)trow*16 + r0] = bb*NCTX + (int)(p0 & 0xFFFFFFFFu);
      if (lane + 64 < S && r1 < 16)
        senders[(size_t)trow*16 + r1] = bb*NCTX + (int)(p1 & 0xFFFFFFFFu);
    } else {
      if (lane == 0) {
        float dist[16]; int ind[16];
        #pragma unroll
        for (int j=0;j<16;++j){ dist[j]=3.4e38f; ind[j]=0; }
        for (int c = 0; c < NCTX; ++c) {
          float2 p = xy[c];
          float ss  = __fadd_rn(__fmul_rn(p.x,p.x), __fmul_rn(p.y,p.y));
          float dot = __fadd_rn(__fmul_rn(qx, p.x), __fmul_rn(qy, p.y));
          float d2  = __fsub_rn(__fadd_rn(qq, ss), __fmul_rn(2.0f, dot));
          if (d2 < dist[15]) {
            float dj = d2; int ij = c;
            #pragma unroll
            for (int j = 0; j < 16; ++j) {
              bool sw = dj < dist[j];
              float td = dist[j]; int ti = ind[j];
              dist[j] = sw ? dj : td;  ind[j] = sw ? ij : ti;
              dj = sw ? td : dj;       ij = sw ? ti : ij;
            }
          }
        }
        for (int j = 0; j < 16; ++j)
          senders[(size_t)trow*16 + j] = bb*NCTX + ind[j];
      }
    }
  } else {
    // ---------------- node_mlp role (id 0..767; wave = one 16-row tile) ---
    // K-halved h1 staging: [16][136] fp16 per phase (4352B) -> slice 4864B.
    const int id = grp*3 + (rr_ - 16);
    char* slice = smem + w * 5120;
    _Float16* h1t  = reinterpret_cast<_Float16*>(slice);     // [16][136]
    float (*xin)[4] = reinterpret_cast<float(*)[4]>(slice + 4608);
    _Float16* h2   = h1t;               // overlay after h1 consumed
    _Float16* nodh = h1t;               // overlay after h2 consumed
    const int cn = lane & 15;
    const int kg = lane >> 4;
    const int m0 = (id*4 + w) * 16;
    const bool is_ctx = (m0 < NCTX_TOT);   // uniform per wave

    const _Float16* bQ2 = W2P + lane*8;
    const _Float16* bQ3 = W3P + lane*8;
    const _Float16* bQg = WgP + lane*8;

    half8 bb2[8];
    #pragma unroll
    for (int j = 0; j < 8; ++j)
      bb2[j] = *reinterpret_cast<const half8*>(bQ2 + j*4096);

    { // stage per-row inputs
      int r = lane >> 2, c = lane & 3;
      int n = m0 + r;
      float v;
      if (is_ctx) v = (c < 2) ? s_ctx[2*(size_t)n + c] : f_ctx[2*(size_t)n + (c-2)];
      else { int tn = n - NCTX_TOT; v = (c < 2) ? s_test[2*(size_t)tn + c] : 0.f; }
      xin[r][c] = v;
    }

    // ---- L1 + L2 in two K-halves (identical per-op math & accum order) ---
    f32x4 acc2[8];
    #pragma unroll
    for (int j = 0; j < 8; ++j) {
      float bv = b2[16*j + cn];
      acc2[j] = (f32x4){bv, bv, bv, bv};
    }
    #pragma unroll
    for (int h = 0; h < 2; ++h) {
      { // L1 half: cols h*128 + lane*2 .. +1
        const int cg = h*128 + lane*2;
        float2 w4 = *reinterpret_cast<const float2*>(&W1[4*256 + cg]);
        float2 w5 = *reinterpret_cast<const float2*>(&W1[5*256 + cg]);
        float2 w6 = *reinterpret_cast<const float2*>(&W1[6*256 + cg]);
        float2 w7 = *reinterpret_cast<const float2*>(&W1[7*256 + cg]);
        float2 cb2 = *reinterpret_cast<const float2*>(&ctype[(is_ctx ? 256 : 0) + cg]);
        #pragma unroll
        for (int r = 0; r < 16; ++r) {
          float4 xi = *reinterpret_cast<const float4*>(&xin[r][0]);
          float ax = cb2.x, ay = cb2.y;
          ax = fmaf(xi.x, w4.x, ax); ay = fmaf(xi.x, w4.y, ay);
          ax = fmaf(xi.y, w5.x, ax); ay = fmaf(xi.y, w5.y, ay);
          ax = fmaf(xi.z, w6.x, ax); ay = fmaf(xi.z, w6.y, ay);
          ax = fmaf(xi.w, w7.x, ax); ay = fmaf(xi.w, w7.y, ay);
          half2v o = { (_Float16)gelu_f(ax), (_Float16)gelu_f(ay) };
          *reinterpret_cast<half2v*>(&h1t[r*136 + lane*2]) = o;
        }
      }
      { // L2 quarter-loop: ks = h*4 + ks2
        const _Float16* aP = h1t + cn*136 + kg*8;
        #pragma unroll
        for (int ks2 = 0; ks2 < 4; ++ks2) {
          const int ks = h*4 + ks2;
          half8 a = *reinterpret_cast<const half8*>(aP + ks2*32);
          half8 bn[8];
          if (ks < 7) {
            #pragma unroll
            for (int j = 0; j < 8; ++j)
              bn[j] = *reinterpret_cast<const half8*>(bQ2 + j*4096 + (ks+1)*512);
          }
          #pragma unroll
          for (int j = 0; j < 8; ++j)
            acc2[j] = __builtin_amdgcn_mfma_f32_16x16x32_f16(a, bb2[j], acc2[j], 0, 0, 0);
          if (ks < 7) {
            #pragma unroll
            for (int j = 0; j < 8; ++j) bb2[j] = bn[j];
          }
        }
      }
    }
    #pragma unroll
    for (int j = 0; j < 8; ++j)
      #pragma unroll
      for (int r = 0; r < 4; ++r) {
        int m = kg*4 + r;
        h2[m*136 + 16*j + cn] = (_Float16)gelu_f(acc2[j][r]);
      }

    { // L3 + LN
      f32x4 acc[4];
      #pragma unroll
      for (int j = 0; j < 4; ++j) {
        float bv = b3[16*j + cn];
        acc[j] = (f32x4){bv, bv, bv, bv};
      }
      const _Float16* aP = h2 + cn*136 + kg*8;
      half8 bb[4];
      #pragma unroll
      for (int j = 0; j < 4; ++j)
        bb[j] = *reinterpret_cast<const half8*>(bQ3 + j*2048);
      #pragma unroll
      for (int ks = 0; ks < 4; ++ks) {
        half8 a = *reinterpret_cast<const half8*>(aP + ks*32);
        half8 bn[4];
        if (ks < 3) {
          #pragma unroll
          for (int j = 0; j < 4; ++j)
            bn[j] = *reinterpret_cast<const half8*>(bQ3 + j*2048 + (ks+1)*512);
        }
        #pragma unroll
        for (int j = 0; j < 4; ++j)
          acc[j] = __builtin_amdgcn_mfma_f32_16x16x32_f16(a, bb[j], acc[j], 0, 0, 0);
        if (ks < 3) {
          #pragma unroll
          for (int j = 0; j < 4; ++j) bb[j] = bn[j];
        }
      }
      float gv[4], bvv[4];
      #pragma unroll
      for (int j = 0; j < 4; ++j) { gv[j] = ln_g[16*j+cn]; bvv[j] = ln_b[16*j+cn]; }
      const bool is_test = !is_ctx;
      #pragma unroll
      for (int r = 0; r < 4; ++r) {
        float sv = 0.f, sq = 0.f;
        #pragma unroll
        for (int j = 0; j < 4; ++j) {
          float v = acc[j][r];
          sv += v; sq += v*v;
        }
        #pragma unroll
        for (int o = 1; o < 16; o <<= 1) {
          sv += __shfl_xor(sv, o);
          sq += __shfl_xor(sq, o);
        }
        float mean = sv * (1.0f/64.0f);
        float var  = sq * (1.0f/64.0f) - mean*mean;
        float rstd = rsqrtf(var + 1e-6f);
        int m = kg*4 + r;
        #pragma unroll
        for (int j = 0; j < 4; ++j) {
          float v = (acc[j][r] - mean) * rstd * gv[j] + bvv[j];
          nodh[m*72 + 16*j + cn] = (_Float16)v;
          if (is_test)
            nodes[(size_t)(m0 + m)*64 + 16*j + cn] = v;
        }
      }
    }

    { // xp(@fp16) = LN @ Wg, plus per-head xps/xpd emission
      f32x4 acc[4];
      #pragma unroll
      for (int j = 0; j < 4; ++j) acc[j] = (f32x4){0.f, 0.f, 0.f, 0.f};
      const _Float16* aP = nodh + cn*72 + kg*8;
      half8 bg0[4], bg1[4];
      #pragma unroll
      for (int j = 0; j < 4; ++j) {
        bg0[j] = *reinterpret_cast<const half8*>(bQg + j*1024);
        bg1[j] = *reinterpret_cast<const half8*>(bQg + j*1024 + 512);
      }
      half8 a0 = *reinterpret_cast<const half8*>(aP);
      half8 a1 = *reinterpret_cast<const half8*>(aP + 32);
      #pragma unroll
      for (int j = 0; j < 4; ++j)
        acc[j] = __builtin_amdgcn_mfma_f32_16x16x32_f16(a0, bg0[j], acc[j], 0, 0, 0);
      #pragma unroll
      for (int j = 0; j < 4; ++j)
        acc[j] = __builtin_amdgcn_mfma_f32_16x16x32_f16(a1, bg1[j], acc[j], 0, 0, 0);
      #pragma unroll
      for (int r = 0; r < 4; ++r) {
        int m = kg*4 + r;
        #pragma unroll
        for (int j = 0; j < 4; ++j)
          xph[(size_t)(m0 + m)*64 + 16*j + cn] = (_Float16)acc[j][r];
      }
      const float* av = is_ctx ? a_src : a_dst;
      float av0 = av[cn], av1 = av[16+cn], av2 = av[32+cn], av3 = av[48+cn];
      #pragma unroll
      for (int r = 0; r < 4; ++r) {
        float p0 = acc[0][r]*av0, p1 = acc[1][r]*av1;
        float p2 = acc[2][r]*av2, p3 = acc[3][r]*av3;
        #pragma unroll
        for (int o = 1; o < 16; o <<= 1) {
          p0 += __shfl_xor(p0, o); p1 += __shfl_xor(p1, o);
          p2 += __shfl_xor(p2, o); p3 += __shfl_xor(p3, o);
        }
        if (cn == 0) {
          int m = kg*4 + r;
          float4 v = make_float4(p0, p1, p2, p3);
          if (is_ctx)
            *reinterpret_cast<float4*>(&xps[(size_t)(m0 + m)*4]) = v;
          else
            *reinterpret_cast<float4*>(&xpd[(size_t)(m0 + m - NCTX_TOT)*4]) = v;
        }
      }
    }
  }
}

// ---------------------------------------------------------------------------
// Back kernel (unchanged): one wave per 16 test rows (grid 1024, block 64,
// XCD-swizzled), barrier-free.
// ---------------------------------------------------------------------------
__global__ __launch_bounds__(64, 3) void back_kernel(
    const float* __restrict__ s_ctx, const float* __restrict__ s_test,
    const _Float16* __restrict__ xph, const int* __restrict__ senders,
    const float* __restrict__ xps, const float* __restrict__ xpd,
    const float* __restrict__ We, const float* __restrict__ be,
    const float* __restrict__ nodes,
    const _Float16* __restrict__ H1P, const float* __restrict__ c1,
    const _Float16* __restrict__ H2P, const float* __restrict__ c2,
    const float* __restrict__ H3, const float* __restrict__ c3,
    float* __restrict__ outp)
{
  __shared__ __align__(16) _Float16 xinh[16*72];   // 2304 B
  __shared__ __align__(16) _Float16 h1[16*264];    // 8448 B
  const int lane = threadIdx.x;       // one wave
  const int cn   = lane & 15;
  const int kg   = lane >> 4;
  const int bid  = blockIdx.x;                    // 1024
  const int L    = (bid & 7)*128 + (bid >> 3);    // XCD-contiguous
  const int row0 = L * 16;                        // test-local row base

  { // ---- attn: 16 rows, score layout lane=(h,kk), h==kg ----
    const int h  = kg;
    const int kk = cn;
    const int hb = lane & 48;
    const float we0 = We[h], we1 = We[4+h], beh = be[h];
    for (int rr = 0; rr < 16; ++rr) {
      const int trow = row0 + rr;
      int s = senders[(size_t)trow*16 + kk];
      s = (s < 0) ? 0 : ((s >= NCTX_TOT) ? NCTX_TOT - 1 : s);  // safety clamp
      float pre = xps[(size_t)s*4 + h] + xpd[(size_t)trow*4 + h];
      float lr  = pre >= 0.f ? pre : 0.2f * pre;
      const float qx = s_test[(size_t)trow*2];
      const float qy = s_test[(size_t)trow*2 + 1];
      float ex = qx - s_ctx[(size_t)s*2];
      float ey = qy - s_ctx[(size_t)s*2 + 1];
      float sc = lr + fmaf(ex, we0, fmaf(ey, we1, beh));
      float mx = sc;
      #pragma unroll
      for (int o = 1; o < 16; o <<= 1) mx = fmaxf(mx, __shfl_xor(mx, o));
      float e = __expf(sc - mx);
      float sum = e;
      #pragma unroll
      for (int o = 1; o < 16; o <<= 1) sum += __shfl_xor(sum, o);
      float alpha = e / sum;
      // PV: lane = h*16+d reads alphas of its head via in-group shfl
      float outv = 0.f;
      #pragma unroll
      for (int k = 0; k < 16; ++k) {
        int   sk = __shfl(s, k);            // same across head groups
        float al = __shfl(alpha, hb + k);
        outv = fmaf(al, (float)xph[(size_t)sk*64 + lane], outv);
      }
      float xv = nodes[(size_t)(NCTX_TOT + trow)*64 + lane] + outv;
      xinh[rr*72 + lane] = (_Float16)xv;
    }
  }

  // ---- head L1 (K=64, N=256) via MFMA, two groups of 8 N-tiles ----
  {
    const _Float16* aP  = xinh + cn*72 + kg*8;
    const _Float16* bQ1 = H1P + lane*8;
    half8 a0 = *reinterpret_cast<const half8*>(aP);
    half8 a1 = *reinterpret_cast<const half8*>(aP + 32);
    #pragma unroll
    for (int g = 0; g < 2; ++g) {
      f32x4 acc[8];
      #pragma unroll
      for (int j = 0; j < 8; ++j) {
        float bv = c1[16*(g*8 + j) + cn];
        acc[j] = (f32x4){bv, bv, bv, bv};
      }
      half8 b0[8], b1[8];
      #pragma unroll
      for (int j = 0; j < 8; ++j) {
        b0[j] = *reinterpret_cast<const half8*>(bQ1 + ((g*8 + j)*2 + 0)*512);
        b1[j] = *reinterpret_cast<const half8*>(bQ1 + ((g*8 + j)*2 + 1)*512);
      }
      #pragma unroll
      for (int j = 0; j < 8; ++j)
        acc[j] = __builtin_amdgcn_mfma_f32_16x16x32_f16(a0, b0[j], acc[j], 0, 0, 0);
      #pragma unroll
      for (int j = 0; j < 8; ++j)
        acc[j] = __builtin_amdgcn_mfma_f32_16x16x32_f16(a1, b1[j], acc[j], 0, 0, 0);
      #pragma unroll
      for (int j = 0; j < 8; ++j)
        #pragma unroll
        for (int r = 0; r < 4; ++r)
          h1[(kg*4 + r)*264 + 16*(g*8 + j) + cn] = (_Float16)gelu_f(acc[j][r]);
    }
  }

  // ---- head L2 (K=256, N=64) via MFMA + L3 (64->2) in-register ----
  {
    f32x4 acc[4];
    #pragma unroll
    for (int j = 0; j < 4; ++j) {
      float bv = c2[16*j + cn];
      acc[j] = (f32x4){bv, bv, bv, bv};
    }
    const _Float16* aP  = h1 + cn*264 + kg*8;
    const _Float16* bQ2 = H2P + lane*8;
    half8 bb[4];
    #pragma unroll
    for (int j = 0; j < 4; ++j)
      bb[j] = *reinterpret_cast<const half8*>(bQ2 + j*4096);
    #pragma unroll
    for (int ks = 0; ks < 8; ++ks) {
      half8 a = *reinterpret_cast<const half8*>(aP + ks*32);
      half8 bn[4];
      if (ks < 7) {
        #pragma unroll
        for (int j = 0; j < 4; ++j)
          bn[j] = *reinterpret_cast<const half8*>(bQ2 + j*4096 + (ks+1)*512);
      }
      #pragma unroll
      for (int j = 0; j < 4; ++j)
        acc[j] = __builtin_amdgcn_mfma_f32_16x16x32_f16(a, bb[j], acc[j], 0, 0, 0);
      if (ks < 7) {
        #pragma unroll
        for (int j = 0; j < 4; ++j) bb[j] = bn[j];
      }
    }
    // L3: gelu on acc, dot with H3 per row, 16-lane butterfly, softplus
    float h30[4], h31[4];
    #pragma unroll
    for (int j = 0; j < 4; ++j) {
      h30[j] = H3[(16*j + cn)*2 + 0];
      h31[j] = H3[(16*j + cn)*2 + 1];
    }
    const float c30 = c3[0], c31 = c3[1];
    #pragma unroll
    for (int r = 0; r < 4; ++r) {
      float p0 = 0.f, p1 = 0.f;
      #pragma unroll
      for (int j = 0; j < 4; ++j) {
        float g = gelu_f(acc[j][r]);
        p0 = fmaf(g, h30[j], p0);
        p1 = fmaf(g, h31[j], p1);
      }
      #pragma unroll
      for (int o = 1; o < 16; o <<= 1) {
        p0 += __shfl_xor(p0, o);
        p1 += __shfl_xor(p1, o);
      }
      if (cn == 0) {
        int row = row0 + kg*4 + r;
        float m = p0 + c30;
        float sa = p1 + c31;
        float sv = fmaxf(sa, 0.f) + log1pf(__expf(-fabsf(sa)));  // softplus
        outp[(size_t)row*2 + 0] = m;
        outp[(size_t)row*2 + 1] = sv;
      }
    }
  }
}

// ---------------------------------------------------------------------------
extern "C" void kernel_launch(void* const* d_in, const int* in_sizes, int n_in,
                              void* d_out, int out_size, void* d_ws, size_t ws_size,
                              hipStream_t stream) {
  const float* s_ctx  = (const float*)d_in[0];
  const float* f_ctx  = (const float*)d_in[1];
  const float* s_test = (const float*)d_in[2];
  const float* emb    = (const float*)d_in[3];
  const float* W1 = (const float*)d_in[4];
  const float* b1 = (const float*)d_in[5];
  const float* W2 = (const float*)d_in[6];
  const float* b2 = (const float*)d_in[7];
  const float* W3 = (const float*)d_in[8];
  const float* b3 = (const float*)d_in[9];
  const float* ln_g = (const float*)d_in[10];
  const float* ln_b = (const float*)d_in[11];
  const float* Wg = (const float*)d_in[12];
  const float* a_src = (const float*)d_in[13];
  const float* a_dst = (const float*)d_in[14];
  const float* We = (const float*)d_in[15];
  const float* be = (const float*)d_in[16];
  const float* H1 = (const float*)d_in[17];
  const float* c1 = (const float*)d_in[18];
  const float* H2 = (const float*)d_in[19];
  const float* c2 = (const float*)d_in[20];
  const float* H3 = (const float*)d_in[21];
  const float* c3 = (const float*)d_in[22];

  float* nodes   = (float*)d_ws;                       // NTOT x 64 fp32
  _Float16* xph  = (_Float16*)(nodes + (size_t)NTOT*64);  // NTOT x 64 fp16
  int*   senders = (int*)(xph + (size_t)NTOT*64);      // NTEST_TOT x 16
  _Float16* W2P  = (_Float16*)(senders + (size_t)NTEST_TOT*16); // 32768 halves
  _Float16* W3P  = W2P + 32768;                        // 8192 halves
  _Float16* WgP  = W3P + 8192;                         // 4096 halves
  _Float16* H1P  = WgP + 4096;                         // 16384 halves
  _Float16* H2P  = H1P + 16384;                        // 16384 halves
  float*   ctype = (float*)(H2P + 16384);              // [2][256]
  float*   xps   = ctype + 512;                        // NCTX_TOT x 4
  float*   xpd   = xps + (size_t)NCTX_TOT*4;           // NTEST_TOT x 4
  float* outp    = (float*)d_out;

  hipLaunchKernelGGL(prep_kernel, dim3(16), dim3(256), 0, stream,
                     W1, b1, emb, W2, W3, Wg, H1, H2,
                     W2P, W3P, WgP, H1P, H2P, ctype);
  hipLaunchKernelGGL(front_kernel, dim3(4864), dim3(256), 0, stream,
                     s_ctx, f_ctx, s_test, senders, ctype, W1,
                     W2P, b2, W3P, b3, ln_g, ln_b, WgP,
                     a_src, a_dst, nodes, xph, xps, xpd);
  hipLaunchKernelGGL(back_kernel, dim3(1024), dim3(64), 0, stream,
                     s_ctx, s_test, xph, senders, xps, xpd, We, be,
                     nodes, H1P, c1, H2P, c2, H3, c3, outp);
}

// Round 3
// 80.835 us; speedup vs baseline: 1.9046x; 1.9046x over previous
//
#include <hip/hip_runtime.h>
#include <math.h>

#define NB 16
#define NCTX 2048
#define NTEST 1024
#define NCTX_TOT (NB*NCTX)      /* 32768 */
#define NTEST_TOT (NB*NTEST)    /* 16384 */
#define NTOT (NCTX_TOT + NTEST_TOT) /* 49152 */

typedef _Float16 half8 __attribute__((ext_vector_type(8)));
typedef _Float16 half4 __attribute__((ext_vector_type(4)));
typedef float f32x4 __attribute__((ext_vector_type(4)));

__device__ __forceinline__ float gelu_f(float x) {
  float x3 = x * x * x;
  float y = 0.7978845608028654f * fmaf(0.044715f, x3, x);
  float e = __expf(2.0f * y);
  float th = 1.0f - 2.0f * __builtin_amdgcn_rcpf(e + 1.0f);
  return 0.5f * x * (1.0f + th);
}

__device__ __forceinline__ void fma4(float4& a, float s, float4 w) {
  a.x = fmaf(s, w.x, a.x);
  a.y = fmaf(s, w.y, a.y);
  a.z = fmaf(s, w.z, a.z);
  a.w = fmaf(s, w.w, a.w);
}

__device__ __forceinline__ float4 ldg4(const float* p) {
  return *reinterpret_cast<const float4*>(p);
}

__device__ __forceinline__ unsigned fkey(float f) {
  unsigned u = __float_as_uint(f);
  return (u & 0x80000000u) ? ~u : (u ^ 0x80000000u);
}
__device__ __forceinline__ float unfkey(unsigned k) {
  return (k & 0x80000000u) ? __uint_as_float(k ^ 0x80000000u)
                           : __uint_as_float(~k);
}

// ---------------------------------------------------------------------------
// Weight prep: fragment-contiguous fp16 packs (W2,W3,Wg + H1,H2) + ctype.
// Pack recipe (proven R10): P[((j*KS+ks)*64+l)*8+e] = fp16(W[(ks*32+(l>>4)*8+e)*N + 16j+(l&15)])
// ---------------------------------------------------------------------------
__global__ __launch_bounds__(256) void prep_kernel(
    const float* __restrict__ W1, const float* __restrict__ b1,
    const float* __restrict__ emb,
    const float* __restrict__ W2, const float* __restrict__ W3,
    const float* __restrict__ Wg,
    const float* __restrict__ H1, const float* __restrict__ H2,
    _Float16* __restrict__ W2P, _Float16* __restrict__ W3P,
    _Float16* __restrict__ WgP,
    _Float16* __restrict__ H1P, _Float16* __restrict__ H2P,
    float* __restrict__ ctype)
{
  int t = blockIdx.x * 256 + threadIdx.x;   // grid 16*256 = 4096
  { // W2: 8 j x 8 ks (N=128, K=256)
    int j = t >> 9, ks = (t >> 6) & 7, l = t & 63;
    int col = 16*j + (l & 15);
    int k0  = ks*32 + (l >> 4)*8;
    half8 o;
    #pragma unroll
    for (int e = 0; e < 8; ++e) o[e] = (_Float16)W2[(k0 + e)*128 + col];
    *reinterpret_cast<half8*>(&W2P[(size_t)t*8]) = o;
  }
  if (t < 1024) { // W3: 4 j x 4 ks (N=64, K=128)
    int j = t >> 8, ks = (t >> 6) & 3, l = t & 63;
    int col = 16*j + (l & 15);
    int k0  = ks*32 + (l >> 4)*8;
    half8 o;
    #pragma unroll
    for (int e = 0; e < 8; ++e) o[e] = (_Float16)W3[(k0 + e)*64 + col];
    *reinterpret_cast<half8*>(&W3P[(size_t)t*8]) = o;
  }
  if (t < 512) { // Wg: 4 j x 2 ks (N=64, K=64)
    int j = t >> 7, ks = (t >> 6) & 1, l = t & 63;
    int col = 16*j + (l & 15);
    int k0  = ks*32 + (l >> 4)*8;
    half8 o;
    #pragma unroll
    for (int e = 0; e < 8; ++e) o[e] = (_Float16)Wg[(k0 + e)*64 + col];
    *reinterpret_cast<half8*>(&WgP[(size_t)t*8]) = o;
  }
  if (t < 2048) { // H1: 16 j x 2 ks (N=256, K=64)
    int j = t >> 7, ks = (t >> 6) & 1, l = t & 63;
    int col = 16*j + (l & 15);
    int k0  = ks*32 + (l >> 4)*8;
    half8 o;
    #pragma unroll
    for (int e = 0; e < 8; ++e) o[e] = (_Float16)H1[(k0 + e)*256 + col];
    *reinterpret_cast<half8*>(&H1P[(size_t)t*8]) = o;
  }
  if (t < 2048) { // H2: 4 j x 8 ks (N=64, K=256)
    int j = t >> 9, ks = (t >> 6) & 7, l = t & 63;
    int col = 16*j + (l & 15);
    int k0  = ks*32 + (l >> 4)*8;
    half8 o;
    #pragma unroll
    for (int e = 0; e < 8; ++e) o[e] = (_Float16)H2[(k0 + e)*64 + col];
    *reinterpret_cast<half8*>(&H2P[(size_t)t*8]) = o;
  }
  if (t < 512) {
    int ty = t >> 8, c = t & 255;
    float acc = b1[c];
    #pragma unroll
    for (int k = 0; k < 4; ++k) acc = fmaf(emb[ty*4 + k], W1[k*256 + c], acc);
    ctype[t] = acc;
  }
}

// ---------------------------------------------------------------------------
// KNN kernel v3: NO LDS staging — ctx points read directly from global
// (s_ctx is 256 KB, L2-resident; xy[it*64+lane] access is fully coalesced
// 512B/wave dwordx2). LDS = 4 KB (per-wave u64 select buffer only), no
// __syncthreads. u64 (key<<32|idx) lexicographic select (R2-verified math).
// launch_bounds(256,6): VGPR cap 84 >> the ~60 this path needs -> no spill.
// ---------------------------------------------------------------------------
__global__ __launch_bounds__(256, 6) void knn_kernel(
    const float* __restrict__ s_ctx, const float* __restrict__ s_test,
    int* __restrict__ senders)
{
  __shared__ __align__(16) unsigned long long sk[4][128];   // 4096 B
  const int t    = threadIdx.x;
  const int lane = t & 63;
  const int w    = t >> 6;                       // 0..3
  const int blk  = blockIdx.x;                   // 0..4095
  const int bb   = blk >> 8;                     // batch
  const int q    = (blk & 255) * 4 + w;          // 0..1023
  const int trow = bb * NTEST + q;

  const float* cb = s_ctx + (size_t)bb * NCTX * 2;
  const float qx = s_test[(size_t)trow*2];
  const float qy = s_test[(size_t)trow*2 + 1];
  const float qq = __fadd_rn(__fmul_rn(qx,qx), __fmul_rn(qy,qy));

  float d[32];
  float mn = 3.4e38f;
  #pragma unroll
  for (int it = 0; it < 32; ++it) {
    float2 p = *reinterpret_cast<const float2*>(&cb[2*(it*64 + lane)]);
    float ss  = __fadd_rn(__fmul_rn(p.x,p.x), __fmul_rn(p.y,p.y));
    float dot = __fadd_rn(__fmul_rn(qx, p.x), __fmul_rn(qy, p.y));
    float d2  = __fsub_rn(__fadd_rn(qq, ss), __fmul_rn(2.0f, dot));
    d[it] = d2;
    mn = fminf(mn, d2);
  }

  unsigned key = fkey(mn);
  unsigned acc = 0u;
  #pragma unroll
  for (int bit = 31; bit >= 0; --bit) {
    unsigned candv = acc | (1u << bit);
    unsigned long long bal = __ballot(key < candv);
    if (__popcll(bal) < 16) acc = candv;
  }
  const float Tf = unfkey(acc);

  int base = 0;
  #pragma unroll
  for (int it = 0; it < 32; ++it) {
    bool pr = (d[it] <= Tf);
    unsigned long long m = __ballot(pr);
    if (pr) {
      int pos = base + __popcll(m & ((1ULL << lane) - 1ULL));
      if (pos < 128)
        sk[w][pos] = ((unsigned long long)fkey(d[it]) << 32)
                   | (unsigned)(it*64 + lane);       // idx in [0,2047]
    }
    base += __popcll(m);
  }
  const int S = base;                   // uniform; S >= 16 guaranteed

  if (S <= 32) {
    // pad remaining slots so the unrolled compare is safe
    if (lane >= S && lane < 32) sk[w][lane] = ~0ULL;
    unsigned long long pm = sk[w][lane & 31];
    int r0 = 0;
    #pragma unroll
    for (int j = 0; j < 32; ++j)
      r0 += (int)(sk[w][j] < pm);       // (key,idx) lexicographic rank
    if (lane < S && r0 < 16)
      senders[(size_t)trow*16 + r0] = bb*NCTX + (int)(pm & 0xFFFFFFFFu);
  } else if (S <= 128) {
    unsigned long long p0 = (lane      < S) ? sk[w][lane]      : ~0ULL;
    unsigned long long p1 = (lane + 64 < S) ? sk[w][lane + 64] : ~0ULL;
    int r0 = 0, r1 = 0;
    for (int j = 0; j < S; ++j) {       // broadcast LDS reads
      unsigned long long kj = sk[w][j];
      r0 += (int)(kj < p0);
      r1 += (int)(kj < p1);
    }
    if (lane < S && r0 < 16)
      senders[(size_t)trow*16 + r0] = bb*NCTX + (int)(p0 & 0xFFFFFFFFu);
    if (lane + 64 < S && r1 < 16)
      senders[(size_t)trow*16 + r1] = bb*NCTX + (int)(p1 & 0xFFFFFFFFu);
  } else {
    if (lane == 0) {
      float dist[16]; int ind[16];
      #pragma unroll
      for (int j=0;j<16;++j){ dist[j]=3.4e38f; ind[j]=0; }
      for (int c = 0; c < NCTX; ++c) {
        float2 p = *reinterpret_cast<const float2*>(&cb[2*c]);
        float ss  = __fadd_rn(__fmul_rn(p.x,p.x), __fmul_rn(p.y,p.y));
        float dot = __fadd_rn(__fmul_rn(qx, p.x), __fmul_rn(qy, p.y));
        float d2  = __fsub_rn(__fadd_rn(qq, ss), __fmul_rn(2.0f, dot));
        if (d2 < dist[15]) {
          float dj = d2; int ij = c;
          #pragma unroll
          for (int j = 0; j < 16; ++j) {
            bool sw = dj < dist[j];
            float td = dist[j]; int ti = ind[j];
            dist[j] = sw ? dj : td;  ind[j] = sw ? ij : ti;
            dj = sw ? td : dj;       ij = sw ? ti : ij;
          }
        }
      }
      for (int j = 0; j < 16; ++j)
        senders[(size_t)trow*16 + j] = bb*NCTX + ind[j];
    }
  }
}

// ---------------------------------------------------------------------------
// node_mlp kernel (R1 verbatim, known-good). grid 768 x 256, each wave owns
// one 16-row tile. LDS 34816; (256,4).
// ---------------------------------------------------------------------------
__global__ __launch_bounds__(256, 4) void mlp_kernel(
    const float* __restrict__ s_ctx, const float* __restrict__ f_ctx,
    const float* __restrict__ s_test,
    const float* __restrict__ ctype, const float* __restrict__ W1,
    const _Float16* __restrict__ W2P, const float* __restrict__ b2,
    const _Float16* __restrict__ W3P, const float* __restrict__ b3,
    const float* __restrict__ ln_g, const float* __restrict__ ln_b,
    const _Float16* __restrict__ WgP,
    const float* __restrict__ a_src, const float* __restrict__ a_dst,
    float* __restrict__ nodes, _Float16* __restrict__ xph,
    float* __restrict__ xps, float* __restrict__ xpd)
{
  __shared__ __align__(16) char smem[34816];
  const int t    = threadIdx.x;
  const int lane = t & 63;
  const int w    = t >> 6;
  const int id   = blockIdx.x;        // 0..767
  char* slice = smem + w * 8704;
  _Float16* h1t  = reinterpret_cast<_Float16*>(slice);     // [16][264]
  float (*xin)[4] = reinterpret_cast<float(*)[4]>(slice + 8448);
  _Float16* h2   = h1t;               // overlay after h1 consumed
  _Float16* nodh = h1t + 16*136;
  const int cn = lane & 15;
  const int kg = lane >> 4;
  const int m0 = (id*4 + w) * 16;
  const bool is_ctx = (m0 < NCTX_TOT);   // uniform per wave

  const _Float16* bQ2 = W2P + lane*8;
  const _Float16* bQ3 = W3P + lane*8;
  const _Float16* bQg = WgP + lane*8;

  half8 bb2[8];
  #pragma unroll
  for (int j = 0; j < 8; ++j)
    bb2[j] = *reinterpret_cast<const half8*>(bQ2 + j*4096);

  { // stage per-row inputs
    int r = lane >> 2, c = lane & 3;
    int n = m0 + r;
    float v;
    if (is_ctx) v = (c < 2) ? s_ctx[2*(size_t)n + c] : f_ctx[2*(size_t)n + (c-2)];
    else { int tn = n - NCTX_TOT; v = (c < 2) ? s_test[2*(size_t)tn + c] : 0.f; }
    xin[r][c] = v;
  }

  { // L1
    const int c0 = lane * 4;
    float4 w4 = ldg4(&W1[4*256 + c0]);
    float4 w5 = ldg4(&W1[5*256 + c0]);
    float4 w6 = ldg4(&W1[6*256 + c0]);
    float4 w7 = ldg4(&W1[7*256 + c0]);
    float4 cbv = ldg4(&ctype[(is_ctx ? 256 : 0) + c0]);
    #pragma unroll
    for (int r = 0; r < 16; ++r) {
      float4 xi = *reinterpret_cast<const float4*>(&xin[r][0]);
      float4 a = cbv;
      fma4(a, xi.x, w4); fma4(a, xi.y, w5);
      fma4(a, xi.z, w6); fma4(a, xi.w, w7);
      half4 o = { (_Float16)gelu_f(a.x), (_Float16)gelu_f(a.y),
                  (_Float16)gelu_f(a.z), (_Float16)gelu_f(a.w) };
      *reinterpret_cast<half4*>(&h1t[r*264 + c0]) = o;
    }
  }

  { // L2
    f32x4 acc[8];
    #pragma unroll
    for (int j = 0; j < 8; ++j) {
      float bv = b2[16*j + cn];
      acc[j] = (f32x4){bv, bv, bv, bv};
    }
    const _Float16* aP = h1t + cn*264 + kg*8;
    #pragma unroll
    for (int ks = 0; ks < 8; ++ks) {
      half8 a = *reinterpret_cast<const half8*>(aP + ks*32);
      half8 bn[8];
      if (ks < 7) {
        #pragma unroll
        for (int j = 0; j < 8; ++j)
          bn[j] = *reinterpret_cast<const half8*>(bQ2 + j*4096 + (ks+1)*512);
      }
      #pragma unroll
      for (int j = 0; j < 8; ++j)
        acc[j] = __builtin_amdgcn_mfma_f32_16x16x32_f16(a, bb2[j], acc[j], 0, 0, 0);
      if (ks < 7) {
        #pragma unroll
        for (int j = 0; j < 8; ++j) bb2[j] = bn[j];
      }
    }
    #pragma unroll
    for (int j = 0; j < 8; ++j)
      #pragma unroll
      for (int r = 0; r < 4; ++r) {
        int m = kg*4 + r;
        h2[m*136 + 16*j + cn] = (_Float16)gelu_f(acc[j][r]);
      }
  }

  { // L3 + LN
    f32x4 acc[4];
    #pragma unroll
    for (int j = 0; j < 4; ++j) {
      float bv = b3[16*j + cn];
      acc[j] = (f32x4){bv, bv, bv, bv};
    }
    const _Float16* aP = h2 + cn*136 + kg*8;
    half8 bb[4];
    #pragma unroll
    for (int j = 0; j < 4; ++j)
      bb[j] = *reinterpret_cast<const half8*>(bQ3 + j*2048);
    #pragma unroll
    for (int ks = 0; ks < 4; ++ks) {
      half8 a = *reinterpret_cast<const half8*>(aP + ks*32);
      half8 bn[4];
      if (ks < 3) {
        #pragma unroll
        for (int j = 0; j < 4; ++j)
          bn[j] = *reinterpret_cast<const half8*>(bQ3 + j*2048 + (ks+1)*512);
      }
      #pragma unroll
      for (int j = 0; j < 4; ++j)
        acc[j] = __builtin_amdgcn_mfma_f32_16x16x32_f16(a, bb[j], acc[j], 0, 0, 0);
      if (ks < 3) {
        #pragma unroll
        for (int j = 0; j < 4; ++j) bb[j] = bn[j];
      }
    }
    float gv[4], bvv[4];
    #pragma unroll
    for (int j = 0; j < 4; ++j) { gv[j] = ln_g[16*j+cn]; bvv[j] = ln_b[16*j+cn]; }
    const bool is_test = !is_ctx;
    #pragma unroll
    for (int r = 0; r < 4; ++r) {
      float sv = 0.f, sq = 0.f;
      #pragma unroll
      for (int j = 0; j < 4; ++j) {
        float v = acc[j][r];
        sv += v; sq += v*v;
      }
      #pragma unroll
      for (int o = 1; o < 16; o <<= 1) {
        sv += __shfl_xor(sv, o);
        sq += __shfl_xor(sq, o);
      }
      float mean = sv * (1.0f/64.0f);
      float var  = sq * (1.0f/64.0f) - mean*mean;
      float rstd = rsqrtf(var + 1e-6f);
      int m = kg*4 + r;
      #pragma unroll
      for (int j = 0; j < 4; ++j) {
        float v = (acc[j][r] - mean) * rstd * gv[j] + bvv[j];
        nodh[m*72 + 16*j + cn] = (_Float16)v;
        if (is_test)
          nodes[(size_t)(m0 + m)*64 + 16*j + cn] = v;
      }
    }
  }

  { // xp(@fp16) = LN @ Wg, plus per-head xps/xpd emission
    f32x4 acc[4];
    #pragma unroll
    for (int j = 0; j < 4; ++j) acc[j] = (f32x4){0.f, 0.f, 0.f, 0.f};
    const _Float16* aP = nodh + cn*72 + kg*8;
    half8 bg0[4], bg1[4];
    #pragma unroll
    for (int j = 0; j < 4; ++j) {
      bg0[j] = *reinterpret_cast<const half8*>(bQg + j*1024);
      bg1[j] = *reinterpret_cast<const half8*>(bQg + j*1024 + 512);
    }
    half8 a0 = *reinterpret_cast<const half8*>(aP);
    half8 a1 = *reinterpret_cast<const half8*>(aP + 32);
    #pragma unroll
    for (int j = 0; j < 4; ++j)
      acc[j] = __builtin_amdgcn_mfma_f32_16x16x32_f16(a0, bg0[j], acc[j], 0, 0, 0);
    #pragma unroll
    for (int j = 0; j < 4; ++j)
      acc[j] = __builtin_amdgcn_mfma_f32_16x16x32_f16(a1, bg1[j], acc[j], 0, 0, 0);
    #pragma unroll
    for (int r = 0; r < 4; ++r) {
      int m = kg*4 + r;
      #pragma unroll
      for (int j = 0; j < 4; ++j)
        xph[(size_t)(m0 + m)*64 + 16*j + cn] = (_Float16)acc[j][r];
    }
    const float* av = is_ctx ? a_src : a_dst;
    float av0 = av[cn], av1 = av[16+cn], av2 = av[32+cn], av3 = av[48+cn];
    #pragma unroll
    for (int r = 0; r < 4; ++r) {
      float p0 = acc[0][r]*av0, p1 = acc[1][r]*av1;
      float p2 = acc[2][r]*av2, p3 = acc[3][r]*av3;
      #pragma unroll
      for (int o = 1; o < 16; o <<= 1) {
        p0 += __shfl_xor(p0, o); p1 += __shfl_xor(p1, o);
        p2 += __shfl_xor(p2, o); p3 += __shfl_xor(p3, o);
      }
      if (cn == 0) {
        int m = kg*4 + r;
        float4 v = make_float4(p0, p1, p2, p3);
        if (is_ctx)
          *reinterpret_cast<float4*>(&xps[(size_t)(m0 + m)*4]) = v;
        else
          *reinterpret_cast<float4*>(&xpd[(size_t)(m0 + m - NCTX_TOT)*4]) = v;
      }
    }
  }
}

// ---------------------------------------------------------------------------
// Back kernel (unchanged): one wave per 16 test rows (grid 1024, block 64,
// XCD-swizzled), barrier-free.
// ---------------------------------------------------------------------------
__global__ __launch_bounds__(64, 3) void back_kernel(
    const float* __restrict__ s_ctx, const float* __restrict__ s_test,
    const _Float16* __restrict__ xph, const int* __restrict__ senders,
    const float* __restrict__ xps, const float* __restrict__ xpd,
    const float* __restrict__ We, const float* __restrict__ be,
    const float* __restrict__ nodes,
    const _Float16* __restrict__ H1P, const float* __restrict__ c1,
    const _Float16* __restrict__ H2P, const float* __restrict__ c2,
    const float* __restrict__ H3, const float* __restrict__ c3,
    float* __restrict__ outp)
{
  __shared__ __align__(16) _Float16 xinh[16*72];   // 2304 B
  __shared__ __align__(16) _Float16 h1[16*264];    // 8448 B
  const int lane = threadIdx.x;       // one wave
  const int cn   = lane & 15;
  const int kg   = lane >> 4;
  const int bid  = blockIdx.x;                    // 1024
  const int L    = (bid & 7)*128 + (bid >> 3);    // XCD-contiguous
  const int row0 = L * 16;                        // test-local row base

  { // ---- attn: 16 rows, score layout lane=(h,kk), h==kg ----
    const int h  = kg;
    const int kk = cn;
    const int hb = lane & 48;
    const float we0 = We[h], we1 = We[4+h], beh = be[h];
    for (int rr = 0; rr < 16; ++rr) {
      const int trow = row0 + rr;
      int s = senders[(size_t)trow*16 + kk];
      s = (s < 0) ? 0 : ((s >= NCTX_TOT) ? NCTX_TOT - 1 : s);  // safety clamp
      float pre = xps[(size_t)s*4 + h] + xpd[(size_t)trow*4 + h];
      float lr  = pre >= 0.f ? pre : 0.2f * pre;
      const float qx = s_test[(size_t)trow*2];
      const float qy = s_test[(size_t)trow*2 + 1];
      float ex = qx - s_ctx[(size_t)s*2];
      float ey = qy - s_ctx[(size_t)s*2 + 1];
      float sc = lr + fmaf(ex, we0, fmaf(ey, we1, beh));
      float mx = sc;
      #pragma unroll
      for (int o = 1; o < 16; o <<= 1) mx = fmaxf(mx, __shfl_xor(mx, o));
      float e = __expf(sc - mx);
      float sum = e;
      #pragma unroll
      for (int o = 1; o < 16; o <<= 1) sum += __shfl_xor(sum, o);
      float alpha = e / sum;
      // PV: lane = h*16+d reads alphas of its head via in-group shfl
      float outv = 0.f;
      #pragma unroll
      for (int k = 0; k < 16; ++k) {
        int   sk = __shfl(s, k);            // same across head groups
        float al = __shfl(alpha, hb + k);
        outv = fmaf(al, (float)xph[(size_t)sk*64 + lane], outv);
      }
      float xv = nodes[(size_t)(NCTX_TOT + trow)*64 + lane] + outv;
      xinh[rr*72 + lane] = (_Float16)xv;
    }
  }

  // ---- head L1 (K=64, N=256) via MFMA, two groups of 8 N-tiles ----
  {
    const _Float16* aP  = xinh + cn*72 + kg*8;
    const _Float16* bQ1 = H1P + lane*8;
    half8 a0 = *reinterpret_cast<const half8*>(aP);
    half8 a1 = *reinterpret_cast<const half8*>(aP + 32);
    #pragma unroll
    for (int g = 0; g < 2; ++g) {
      f32x4 acc[8];
      #pragma unroll
      for (int j = 0; j < 8; ++j) {
        float bv = c1[16*(g*8 + j) + cn];
        acc[j] = (f32x4){bv, bv, bv, bv};
      }
      half8 b0[8], b1[8];
      #pragma unroll
      for (int j = 0; j < 8; ++j) {
        b0[j] = *reinterpret_cast<const half8*>(bQ1 + ((g*8 + j)*2 + 0)*512);
        b1[j] = *reinterpret_cast<const half8*>(bQ1 + ((g*8 + j)*2 + 1)*512);
      }
      #pragma unroll
      for (int j = 0; j < 8; ++j)
        acc[j] = __builtin_amdgcn_mfma_f32_16x16x32_f16(a0, b0[j], acc[j], 0, 0, 0);
      #pragma unroll
      for (int j = 0; j < 8; ++j)
        acc[j] = __builtin_amdgcn_mfma_f32_16x16x32_f16(a1, b1[j], acc[j], 0, 0, 0);
      #pragma unroll
      for (int j = 0; j < 8; ++j)
        #pragma unroll
        for (int r = 0; r < 4; ++r)
          h1[(kg*4 + r)*264 + 16*(g*8 + j) + cn] = (_Float16)gelu_f(acc[j][r]);
    }
  }

  // ---- head L2 (K=256, N=64) via MFMA + L3 (64->2) in-register ----
  {
    f32x4 acc[4];
    #pragma unroll
    for (int j = 0; j < 4; ++j) {
      float bv = c2[16*j + cn];
      acc[j] = (f32x4){bv, bv, bv, bv};
    }
    const _Float16* aP  = h1 + cn*264 + kg*8;
    const _Float16* bQ2 = H2P + lane*8;
    half8 bb[4];
    #pragma unroll
    for (int j = 0; j < 4; ++j)
      bb[j] = *reinterpret_cast<const half8*>(bQ2 + j*4096);
    #pragma unroll
    for (int ks = 0; ks < 8; ++ks) {
      half8 a = *reinterpret_cast<const half8*>(aP + ks*32);
      half8 bn[4];
      if (ks < 7) {
        #pragma unroll
        for (int j = 0; j < 4; ++j)
          bn[j] = *reinterpret_cast<const half8*>(bQ2 + j*4096 + (ks+1)*512);
      }
      #pragma unroll
      for (int j = 0; j < 4; ++j)
        acc[j] = __builtin_amdgcn_mfma_f32_16x16x32_f16(a, bb[j], acc[j], 0, 0, 0);
      if (ks < 7) {
        #pragma unroll
        for (int j = 0; j < 4; ++j) bb[j] = bn[j];
      }
    }
    // L3: gelu on acc, dot with H3 per row, 16-lane butterfly, softplus
    float h30[4], h31[4];
    #pragma unroll
    for (int j = 0; j < 4; ++j) {
      h30[j] = H3[(16*j + cn)*2 + 0];
      h31[j] = H3[(16*j + cn)*2 + 1];
    }
    const float c30 = c3[0], c31 = c3[1];
    #pragma unroll
    for (int r = 0; r < 4; ++r) {
      float p0 = 0.f, p1 = 0.f;
      #pragma unroll
      for (int j = 0; j < 4; ++j) {
        float g = gelu_f(acc[j][r]);
        p0 = fmaf(g, h30[j], p0);
        p1 = fmaf(g, h31[j], p1);
      }
      #pragma unroll
      for (int o = 1; o < 16; o <<= 1) {
        p0 += __shfl_xor(p0, o);
        p1 += __shfl_xor(p1, o);
      }
      if (cn == 0) {
        int row = row0 + kg*4 + r;
        float m = p0 + c30;
        float sa = p1 + c31;
        float sv = fmaxf(sa, 0.f) + log1pf(__expf(-fabsf(sa)));  // softplus
        outp[(size_t)row*2 + 0] = m;
        outp[(size_t)row*2 + 1] = sv;
      }
    }
  }
}

// ---------------------------------------------------------------------------
extern "C" void kernel_launch(void* const* d_in, const int* in_sizes, int n_in,
                              void* d_out, int out_size, void* d_ws, size_t ws_size,
                              hipStream_t stream) {
  const float* s_ctx  = (const float*)d_in[0];
  const float* f_ctx  = (const float*)d_in[1];
  const float* s_test = (const float*)d_in[2];
  const float* emb    = (const float*)d_in[3];
  const float* W1 = (const float*)d_in[4];
  const float* b1 = (const float*)d_in[5];
  const float* W2 = (const float*)d_in[6];
  const float* b2 = (const float*)d_in[7];
  const float* W3 = (const float*)d_in[8];
  const float* b3 = (const float*)d_in[9];
  const float* ln_g = (const float*)d_in[10];
  const float* ln_b = (const float*)d_in[11];
  const float* Wg = (const float*)d_in[12];
  const float* a_src = (const float*)d_in[13];
  const float* a_dst = (const float*)d_in[14];
  const float* We = (const float*)d_in[15];
  const float* be = (const float*)d_in[16];
  const float* H1 = (const float*)d_in[17];
  const float* c1 = (const float*)d_in[18];
  const float* H2 = (const float*)d_in[19];
  const float* c2 = (const float*)d_in[20];
  const float* H3 = (const float*)d_in[21];
  const float* c3 = (const float*)d_in[22];

  float* nodes   = (float*)d_ws;                       // NTOT x 64 fp32
  _Float16* xph  = (_Float16*)(nodes + (size_t)NTOT*64);  // NTOT x 64 fp16
  int*   senders = (int*)(xph + (size_t)NTOT*64);      // NTEST_TOT x 16
  _Float16* W2P  = (_Float16*)(senders + (size_t)NTEST_TOT*16); // 32768 halves
  _Float16* W3P  = W2P + 32768;                        // 8192 halves
  _Float16* WgP  = W3P + 8192;                         // 4096 halves
  _Float16* H1P  = WgP + 4096;                         // 16384 halves
  _Float16* H2P  = H1P + 16384;                        // 16384 halves
  float*   ctype = (float*)(H2P + 16384);              // [2][256]
  float*   xps   = ctype + 512;                        // NCTX_TOT x 4
  float*   xpd   = xps + (size_t)NCTX_TOT*4;           // NTEST_TOT x 4
  float* outp    = (float*)d_out;

  hipLaunchKernelGGL(prep_kernel, dim3(16), dim3(256), 0, stream,
                     W1, b1, emb, W2, W3, Wg, H1, H2,
                     W2P, W3P, WgP, H1P, H2P, ctype);
  hipLaunchKernelGGL(knn_kernel, dim3(4096), dim3(256), 0, stream,
                     s_ctx, s_test, senders);
  hipLaunchKernelGGL(mlp_kernel, dim3(768), dim3(256), 0, stream,
                     s_ctx, f_ctx, s_test, ctype, W1,
                     W2P, b2, W3P, b3, ln_g, ln_b, WgP,
                     a_src, a_dst, nodes, xph, xps, xpd);
  hipLaunchKernelGGL(back_kernel, dim3(1024), dim3(64), 0, stream,
                     s_ctx, s_test, xph, senders, xps, xpd, We, be,
                     nodes, H1P, c1, H2P, c2, H3, c3, outp);
}

// Round 4
// 76.957 us; speedup vs baseline: 2.0006x; 1.0504x over previous
//
#include <hip/hip_runtime.h>
#include <math.h>

#define NB 16
#define NCTX 2048
#define NTEST 1024
#define NCTX_TOT (NB*NCTX)      /* 32768 */
#define NTEST_TOT (NB*NTEST)    /* 16384 */
#define NTOT (NCTX_TOT + NTEST_TOT) /* 49152 */

typedef _Float16 half8 __attribute__((ext_vector_type(8)));
typedef _Float16 half4 __attribute__((ext_vector_type(4)));
typedef float f32x4 __attribute__((ext_vector_type(4)));

__device__ __forceinline__ float gelu_f(float x) {
  float x3 = x * x * x;
  float y = 0.7978845608028654f * fmaf(0.044715f, x3, x);
  float e = __expf(2.0f * y);
  float th = 1.0f - 2.0f * __builtin_amdgcn_rcpf(e + 1.0f);
  return 0.5f * x * (1.0f + th);
}

__device__ __forceinline__ void fma4(float4& a, float s, float4 w) {
  a.x = fmaf(s, w.x, a.x);
  a.y = fmaf(s, w.y, a.y);
  a.z = fmaf(s, w.z, a.z);
  a.w = fmaf(s, w.w, a.w);
}

__device__ __forceinline__ float4 ldg4(const float* p) {
  return *reinterpret_cast<const float4*>(p);
}

__device__ __forceinline__ unsigned fkey(float f) {
  unsigned u = __float_as_uint(f);
  return (u & 0x80000000u) ? ~u : (u ^ 0x80000000u);
}
__device__ __forceinline__ float unfkey(unsigned k) {
  return (k & 0x80000000u) ? __uint_as_float(k ^ 0x80000000u)
                           : __uint_as_float(~k);
}

// ---------------------------------------------------------------------------
// Weight prep: fragment-contiguous fp16 packs (W2,W3,Wg + H1,H2) + ctype.
// Pack recipe (proven R10): P[((j*KS+ks)*64+l)*8+e] = fp16(W[(ks*32+(l>>4)*8+e)*N + 16j+(l&15)])
// ---------------------------------------------------------------------------
__global__ __launch_bounds__(256) void prep_kernel(
    const float* __restrict__ W1, const float* __restrict__ b1,
    const float* __restrict__ emb,
    const float* __restrict__ W2, const float* __restrict__ W3,
    const float* __restrict__ Wg,
    const float* __restrict__ H1, const float* __restrict__ H2,
    _Float16* __restrict__ W2P, _Float16* __restrict__ W3P,
    _Float16* __restrict__ WgP,
    _Float16* __restrict__ H1P, _Float16* __restrict__ H2P,
    float* __restrict__ ctype)
{
  int t = blockIdx.x * 256 + threadIdx.x;   // grid 16*256 = 4096
  { // W2: 8 j x 8 ks (N=128, K=256)
    int j = t >> 9, ks = (t >> 6) & 7, l = t & 63;
    int col = 16*j + (l & 15);
    int k0  = ks*32 + (l >> 4)*8;
    half8 o;
    #pragma unroll
    for (int e = 0; e < 8; ++e) o[e] = (_Float16)W2[(k0 + e)*128 + col];
    *reinterpret_cast<half8*>(&W2P[(size_t)t*8]) = o;
  }
  if (t < 1024) { // W3: 4 j x 4 ks (N=64, K=128)
    int j = t >> 8, ks = (t >> 6) & 3, l = t & 63;
    int col = 16*j + (l & 15);
    int k0  = ks*32 + (l >> 4)*8;
    half8 o;
    #pragma unroll
    for (int e = 0; e < 8; ++e) o[e] = (_Float16)W3[(k0 + e)*64 + col];
    *reinterpret_cast<half8*>(&W3P[(size_t)t*8]) = o;
  }
  if (t < 512) { // Wg: 4 j x 2 ks (N=64, K=64)
    int j = t >> 7, ks = (t >> 6) & 1, l = t & 63;
    int col = 16*j + (l & 15);
    int k0  = ks*32 + (l >> 4)*8;
    half8 o;
    #pragma unroll
    for (int e = 0; e < 8; ++e) o[e] = (_Float16)Wg[(k0 + e)*64 + col];
    *reinterpret_cast<half8*>(&WgP[(size_t)t*8]) = o;
  }
  if (t < 2048) { // H1: 16 j x 2 ks (N=256, K=64)
    int j = t >> 7, ks = (t >> 6) & 1, l = t & 63;
    int col = 16*j + (l & 15);
    int k0  = ks*32 + (l >> 4)*8;
    half8 o;
    #pragma unroll
    for (int e = 0; e < 8; ++e) o[e] = (_Float16)H1[(k0 + e)*256 + col];
    *reinterpret_cast<half8*>(&H1P[(size_t)t*8]) = o;
  }
  if (t < 2048) { // H2: 4 j x 8 ks (N=64, K=256)
    int j = t >> 9, ks = (t >> 6) & 7, l = t & 63;
    int col = 16*j + (l & 15);
    int k0  = ks*32 + (l >> 4)*8;
    half8 o;
    #pragma unroll
    for (int e = 0; e < 8; ++e) o[e] = (_Float16)H2[(k0 + e)*64 + col];
    *reinterpret_cast<half8*>(&H2P[(size_t)t*8]) = o;
  }
  if (t < 512) {
    int ty = t >> 8, c = t & 255;
    float acc = b1[c];
    #pragma unroll
    for (int k = 0; k < 4; ++k) acc = fmaf(emb[ty*4 + k], W1[k*256 + c], acc);
    ctype[t] = acc;
  }
}

// ---------------------------------------------------------------------------
// KNN kernel v3 (R3 verbatim, known-good): no LDS staging, global L2 reads,
// u64 (key<<32|idx) lexicographic select.
// ---------------------------------------------------------------------------
__global__ __launch_bounds__(256, 6) void knn_kernel(
    const float* __restrict__ s_ctx, const float* __restrict__ s_test,
    int* __restrict__ senders)
{
  __shared__ __align__(16) unsigned long long sk[4][128];   // 4096 B
  const int t    = threadIdx.x;
  const int lane = t & 63;
  const int w    = t >> 6;                       // 0..3
  const int blk  = blockIdx.x;                   // 0..4095
  const int bb   = blk >> 8;                     // batch
  const int q    = (blk & 255) * 4 + w;          // 0..1023
  const int trow = bb * NTEST + q;

  const float* cb = s_ctx + (size_t)bb * NCTX * 2;
  const float qx = s_test[(size_t)trow*2];
  const float qy = s_test[(size_t)trow*2 + 1];
  const float qq = __fadd_rn(__fmul_rn(qx,qx), __fmul_rn(qy,qy));

  float d[32];
  float mn = 3.4e38f;
  #pragma unroll
  for (int it = 0; it < 32; ++it) {
    float2 p = *reinterpret_cast<const float2*>(&cb[2*(it*64 + lane)]);
    float ss  = __fadd_rn(__fmul_rn(p.x,p.x), __fmul_rn(p.y,p.y));
    float dot = __fadd_rn(__fmul_rn(qx, p.x), __fmul_rn(qy, p.y));
    float d2  = __fsub_rn(__fadd_rn(qq, ss), __fmul_rn(2.0f, dot));
    d[it] = d2;
    mn = fminf(mn, d2);
  }

  unsigned key = fkey(mn);
  unsigned acc = 0u;
  #pragma unroll
  for (int bit = 31; bit >= 0; --bit) {
    unsigned candv = acc | (1u << bit);
    unsigned long long bal = __ballot(key < candv);
    if (__popcll(bal) < 16) acc = candv;
  }
  const float Tf = unfkey(acc);

  int base = 0;
  #pragma unroll
  for (int it = 0; it < 32; ++it) {
    bool pr = (d[it] <= Tf);
    unsigned long long m = __ballot(pr);
    if (pr) {
      int pos = base + __popcll(m & ((1ULL << lane) - 1ULL));
      if (pos < 128)
        sk[w][pos] = ((unsigned long long)fkey(d[it]) << 32)
                   | (unsigned)(it*64 + lane);       // idx in [0,2047]
    }
    base += __popcll(m);
  }
  const int S = base;                   // uniform; S >= 16 guaranteed

  if (S <= 32) {
    // pad remaining slots so the unrolled compare is safe
    if (lane >= S && lane < 32) sk[w][lane] = ~0ULL;
    unsigned long long pm = sk[w][lane & 31];
    int r0 = 0;
    #pragma unroll
    for (int j = 0; j < 32; ++j)
      r0 += (int)(sk[w][j] < pm);       // (key,idx) lexicographic rank
    if (lane < S && r0 < 16)
      senders[(size_t)trow*16 + r0] = bb*NCTX + (int)(pm & 0xFFFFFFFFu);
  } else if (S <= 128) {
    unsigned long long p0 = (lane      < S) ? sk[w][lane]      : ~0ULL;
    unsigned long long p1 = (lane + 64 < S) ? sk[w][lane + 64] : ~0ULL;
    int r0 = 0, r1 = 0;
    for (int j = 0; j < S; ++j) {       // broadcast LDS reads
      unsigned long long kj = sk[w][j];
      r0 += (int)(kj < p0);
      r1 += (int)(kj < p1);
    }
    if (lane < S && r0 < 16)
      senders[(size_t)trow*16 + r0] = bb*NCTX + (int)(p0 & 0xFFFFFFFFu);
    if (lane + 64 < S && r1 < 16)
      senders[(size_t)trow*16 + r1] = bb*NCTX + (int)(p1 & 0xFFFFFFFFu);
  } else {
    if (lane == 0) {
      float dist[16]; int ind[16];
      #pragma unroll
      for (int j=0;j<16;++j){ dist[j]=3.4e38f; ind[j]=0; }
      for (int c = 0; c < NCTX; ++c) {
        float2 p = *reinterpret_cast<const float2*>(&cb[2*c]);
        float ss  = __fadd_rn(__fmul_rn(p.x,p.x), __fmul_rn(p.y,p.y));
        float dot = __fadd_rn(__fmul_rn(qx, p.x), __fmul_rn(qy, p.y));
        float d2  = __fsub_rn(__fadd_rn(qq, ss), __fmul_rn(2.0f, dot));
        if (d2 < dist[15]) {
          float dj = d2; int ij = c;
          #pragma unroll
          for (int j = 0; j < 16; ++j) {
            bool sw = dj < dist[j];
            float td = dist[j]; int ti = ind[j];
            dist[j] = sw ? dj : td;  ind[j] = sw ? ij : ti;
            dj = sw ? td : dj;       ij = sw ? ti : ij;
          }
        }
      }
      for (int j = 0; j < 16; ++j)
        senders[(size_t)trow*16 + j] = bb*NCTX + ind[j];
    }
  }
}

// ---------------------------------------------------------------------------
// node_mlp kernel (R1 verbatim, known-good). grid 768 x 256, each wave owns
// one 16-row tile. LDS 34816; (256,4).
// ---------------------------------------------------------------------------
__global__ __launch_bounds__(256, 4) void mlp_kernel(
    const float* __restrict__ s_ctx, const float* __restrict__ f_ctx,
    const float* __restrict__ s_test,
    const float* __restrict__ ctype, const float* __restrict__ W1,
    const _Float16* __restrict__ W2P, const float* __restrict__ b2,
    const _Float16* __restrict__ W3P, const float* __restrict__ b3,
    const float* __restrict__ ln_g, const float* __restrict__ ln_b,
    const _Float16* __restrict__ WgP,
    const float* __restrict__ a_src, const float* __restrict__ a_dst,
    float* __restrict__ nodes, _Float16* __restrict__ xph,
    float* __restrict__ xps, float* __restrict__ xpd)
{
  __shared__ __align__(16) char smem[34816];
  const int t    = threadIdx.x;
  const int lane = t & 63;
  const int w    = t >> 6;
  const int id   = blockIdx.x;        // 0..767
  char* slice = smem + w * 8704;
  _Float16* h1t  = reinterpret_cast<_Float16*>(slice);     // [16][264]
  float (*xin)[4] = reinterpret_cast<float(*)[4]>(slice + 8448);
  _Float16* h2   = h1t;               // overlay after h1 consumed
  _Float16* nodh = h1t + 16*136;
  const int cn = lane & 15;
  const int kg = lane >> 4;
  const int m0 = (id*4 + w) * 16;
  const bool is_ctx = (m0 < NCTX_TOT);   // uniform per wave

  const _Float16* bQ2 = W2P + lane*8;
  const _Float16* bQ3 = W3P + lane*8;
  const _Float16* bQg = WgP + lane*8;

  half8 bb2[8];
  #pragma unroll
  for (int j = 0; j < 8; ++j)
    bb2[j] = *reinterpret_cast<const half8*>(bQ2 + j*4096);

  { // stage per-row inputs
    int r = lane >> 2, c = lane & 3;
    int n = m0 + r;
    float v;
    if (is_ctx) v = (c < 2) ? s_ctx[2*(size_t)n + c] : f_ctx[2*(size_t)n + (c-2)];
    else { int tn = n - NCTX_TOT; v = (c < 2) ? s_test[2*(size_t)tn + c] : 0.f; }
    xin[r][c] = v;
  }

  { // L1
    const int c0 = lane * 4;
    float4 w4 = ldg4(&W1[4*256 + c0]);
    float4 w5 = ldg4(&W1[5*256 + c0]);
    float4 w6 = ldg4(&W1[6*256 + c0]);
    float4 w7 = ldg4(&W1[7*256 + c0]);
    float4 cbv = ldg4(&ctype[(is_ctx ? 256 : 0) + c0]);
    #pragma unroll
    for (int r = 0; r < 16; ++r) {
      float4 xi = *reinterpret_cast<const float4*>(&xin[r][0]);
      float4 a = cbv;
      fma4(a, xi.x, w4); fma4(a, xi.y, w5);
      fma4(a, xi.z, w6); fma4(a, xi.w, w7);
      half4 o = { (_Float16)gelu_f(a.x), (_Float16)gelu_f(a.y),
                  (_Float16)gelu_f(a.z), (_Float16)gelu_f(a.w) };
      *reinterpret_cast<half4*>(&h1t[r*264 + c0]) = o;
    }
  }

  { // L2
    f32x4 acc[8];
    #pragma unroll
    for (int j = 0; j < 8; ++j) {
      float bv = b2[16*j + cn];
      acc[j] = (f32x4){bv, bv, bv, bv};
    }
    const _Float16* aP = h1t + cn*264 + kg*8;
    #pragma unroll
    for (int ks = 0; ks < 8; ++ks) {
      half8 a = *reinterpret_cast<const half8*>(aP + ks*32);
      half8 bn[8];
      if (ks < 7) {
        #pragma unroll
        for (int j = 0; j < 8; ++j)
          bn[j] = *reinterpret_cast<const half8*>(bQ2 + j*4096 + (ks+1)*512);
      }
      #pragma unroll
      for (int j = 0; j < 8; ++j)
        acc[j] = __builtin_amdgcn_mfma_f32_16x16x32_f16(a, bb2[j], acc[j], 0, 0, 0);
      if (ks < 7) {
        #pragma unroll
        for (int j = 0; j < 8; ++j) bb2[j] = bn[j];
      }
    }
    #pragma unroll
    for (int j = 0; j < 8; ++j)
      #pragma unroll
      for (int r = 0; r < 4; ++r) {
        int m = kg*4 + r;
        h2[m*136 + 16*j + cn] = (_Float16)gelu_f(acc[j][r]);
      }
  }

  { // L3 + LN
    f32x4 acc[4];
    #pragma unroll
    for (int j = 0; j < 4; ++j) {
      float bv = b3[16*j + cn];
      acc[j] = (f32x4){bv, bv, bv, bv};
    }
    const _Float16* aP = h2 + cn*136 + kg*8;
    half8 bb[4];
    #pragma unroll
    for (int j = 0; j < 4; ++j)
      bb[j] = *reinterpret_cast<const half8*>(bQ3 + j*2048);
    #pragma unroll
    for (int ks = 0; ks < 4; ++ks) {
      half8 a = *reinterpret_cast<const half8*>(aP + ks*32);
      half8 bn[4];
      if (ks < 3) {
        #pragma unroll
        for (int j = 0; j < 4; ++j)
          bn[j] = *reinterpret_cast<const half8*>(bQ3 + j*2048 + (ks+1)*512);
      }
      #pragma unroll
      for (int j = 0; j < 4; ++j)
        acc[j] = __builtin_amdgcn_mfma_f32_16x16x32_f16(a, bb[j], acc[j], 0, 0, 0);
      if (ks < 3) {
        #pragma unroll
        for (int j = 0; j < 4; ++j) bb[j] = bn[j];
      }
    }
    float gv[4], bvv[4];
    #pragma unroll
    for (int j = 0; j < 4; ++j) { gv[j] = ln_g[16*j+cn]; bvv[j] = ln_b[16*j+cn]; }
    const bool is_test = !is_ctx;
    #pragma unroll
    for (int r = 0; r < 4; ++r) {
      float sv = 0.f, sq = 0.f;
      #pragma unroll
      for (int j = 0; j < 4; ++j) {
        float v = acc[j][r];
        sv += v; sq += v*v;
      }
      #pragma unroll
      for (int o = 1; o < 16; o <<= 1) {
        sv += __shfl_xor(sv, o);
        sq += __shfl_xor(sq, o);
      }
      float mean = sv * (1.0f/64.0f);
      float var  = sq * (1.0f/64.0f) - mean*mean;
      float rstd = rsqrtf(var + 1e-6f);
      int m = kg*4 + r;
      #pragma unroll
      for (int j = 0; j < 4; ++j) {
        float v = (acc[j][r] - mean) * rstd * gv[j] + bvv[j];
        nodh[m*72 + 16*j + cn] = (_Float16)v;
        if (is_test)
          nodes[(size_t)(m0 + m)*64 + 16*j + cn] = v;
      }
    }
  }

  { // xp(@fp16) = LN @ Wg, plus per-head xps/xpd emission
    f32x4 acc[4];
    #pragma unroll
    for (int j = 0; j < 4; ++j) acc[j] = (f32x4){0.f, 0.f, 0.f, 0.f};
    const _Float16* aP = nodh + cn*72 + kg*8;
    half8 bg0[4], bg1[4];
    #pragma unroll
    for (int j = 0; j < 4; ++j) {
      bg0[j] = *reinterpret_cast<const half8*>(bQg + j*1024);
      bg1[j] = *reinterpret_cast<const half8*>(bQg + j*1024 + 512);
    }
    half8 a0 = *reinterpret_cast<const half8*>(aP);
    half8 a1 = *reinterpret_cast<const half8*>(aP + 32);
    #pragma unroll
    for (int j = 0; j < 4; ++j)
      acc[j] = __builtin_amdgcn_mfma_f32_16x16x32_f16(a0, bg0[j], acc[j], 0, 0, 0);
    #pragma unroll
    for (int j = 0; j < 4; ++j)
      acc[j] = __builtin_amdgcn_mfma_f32_16x16x32_f16(a1, bg1[j], acc[j], 0, 0, 0);
    #pragma unroll
    for (int r = 0; r < 4; ++r) {
      int m = kg*4 + r;
      #pragma unroll
      for (int j = 0; j < 4; ++j)
        xph[(size_t)(m0 + m)*64 + 16*j + cn] = (_Float16)acc[j][r];
    }
    const float* av = is_ctx ? a_src : a_dst;
    float av0 = av[cn], av1 = av[16+cn], av2 = av[32+cn], av3 = av[48+cn];
    #pragma unroll
    for (int r = 0; r < 4; ++r) {
      float p0 = acc[0][r]*av0, p1 = acc[1][r]*av1;
      float p2 = acc[2][r]*av2, p3 = acc[3][r]*av3;
      #pragma unroll
      for (int o = 1; o < 16; o <<= 1) {
        p0 += __shfl_xor(p0, o); p1 += __shfl_xor(p1, o);
        p2 += __shfl_xor(p2, o); p3 += __shfl_xor(p3, o);
      }
      if (cn == 0) {
        int m = kg*4 + r;
        float4 v = make_float4(p0, p1, p2, p3);
        if (is_ctx)
          *reinterpret_cast<float4*>(&xps[(size_t)(m0 + m)*4]) = v;
        else
          *reinterpret_cast<float4*>(&xpd[(size_t)(m0 + m - NCTX_TOT)*4]) = v;
      }
    }
  }
}

// ---------------------------------------------------------------------------
// Back kernel R4: 8 test rows per wave (was 16), grid 2048 -> 8 waves/CU
// (was 4). Attn serial chain per wave halves; 2 waves/SIMD hide gather
// latency. MFMA tiles stay 16x16: A rows 8-15 zero-filled in LDS (valid
// rows' outputs bit-identical; garbage rows finite + write-guarded).
// ---------------------------------------------------------------------------
__global__ __launch_bounds__(64, 3) void back_kernel(
    const float* __restrict__ s_ctx, const float* __restrict__ s_test,
    const _Float16* __restrict__ xph, const int* __restrict__ senders,
    const float* __restrict__ xps, const float* __restrict__ xpd,
    const float* __restrict__ We, const float* __restrict__ be,
    const float* __restrict__ nodes,
    const _Float16* __restrict__ H1P, const float* __restrict__ c1,
    const _Float16* __restrict__ H2P, const float* __restrict__ c2,
    const float* __restrict__ H3, const float* __restrict__ c3,
    float* __restrict__ outp)
{
  __shared__ __align__(16) _Float16 xinh[16*72];   // 2304 B (rows 8-15 zeroed)
  __shared__ __align__(16) _Float16 h1[16*264];    // 8448 B
  const int lane = threadIdx.x;       // one wave
  const int cn   = lane & 15;
  const int kg   = lane >> 4;
  const int bid  = blockIdx.x;                    // 2048
  const int L    = (bid & 7)*256 + (bid >> 3);    // XCD-contiguous
  const int row0 = L * 8;                         // test-local row base

  // zero A rows 8-15 (single wave: program order suffices, no barrier)
  #pragma unroll
  for (int rr = 8; rr < 16; ++rr) xinh[rr*72 + lane] = (_Float16)0.f;

  { // ---- attn: 8 rows, score layout lane=(h,kk), h==kg ----
    const int h  = kg;
    const int kk = cn;
    const int hb = lane & 48;
    const float we0 = We[h], we1 = We[4+h], beh = be[h];
    for (int rr = 0; rr < 8; ++rr) {
      const int trow = row0 + rr;
      int s = senders[(size_t)trow*16 + kk];
      s = (s < 0) ? 0 : ((s >= NCTX_TOT) ? NCTX_TOT - 1 : s);  // safety clamp
      float pre = xps[(size_t)s*4 + h] + xpd[(size_t)trow*4 + h];
      float lr  = pre >= 0.f ? pre : 0.2f * pre;
      const float qx = s_test[(size_t)trow*2];
      const float qy = s_test[(size_t)trow*2 + 1];
      float ex = qx - s_ctx[(size_t)s*2];
      float ey = qy - s_ctx[(size_t)s*2 + 1];
      float sc = lr + fmaf(ex, we0, fmaf(ey, we1, beh));
      float mx = sc;
      #pragma unroll
      for (int o = 1; o < 16; o <<= 1) mx = fmaxf(mx, __shfl_xor(mx, o));
      float e = __expf(sc - mx);
      float sum = e;
      #pragma unroll
      for (int o = 1; o < 16; o <<= 1) sum += __shfl_xor(sum, o);
      float alpha = e / sum;
      // PV: lane = h*16+d reads alphas of its head via in-group shfl
      float outv = 0.f;
      #pragma unroll
      for (int k = 0; k < 16; ++k) {
        int   sk = __shfl(s, k);            // same across head groups
        float al = __shfl(alpha, hb + k);
        outv = fmaf(al, (float)xph[(size_t)sk*64 + lane], outv);
      }
      float xv = nodes[(size_t)(NCTX_TOT + trow)*64 + lane] + outv;
      xinh[rr*72 + lane] = (_Float16)xv;
    }
  }

  // ---- head L1 (K=64, N=256) via MFMA, two groups of 8 N-tiles ----
  {
    const _Float16* aP  = xinh + cn*72 + kg*8;
    const _Float16* bQ1 = H1P + lane*8;
    half8 a0 = *reinterpret_cast<const half8*>(aP);
    half8 a1 = *reinterpret_cast<const half8*>(aP + 32);
    #pragma unroll
    for (int g = 0; g < 2; ++g) {
      f32x4 acc[8];
      #pragma unroll
      for (int j = 0; j < 8; ++j) {
        float bv = c1[16*(g*8 + j) + cn];
        acc[j] = (f32x4){bv, bv, bv, bv};
      }
      half8 b0[8], b1[8];
      #pragma unroll
      for (int j = 0; j < 8; ++j) {
        b0[j] = *reinterpret_cast<const half8*>(bQ1 + ((g*8 + j)*2 + 0)*512);
        b1[j] = *reinterpret_cast<const half8*>(bQ1 + ((g*8 + j)*2 + 1)*512);
      }
      #pragma unroll
      for (int j = 0; j < 8; ++j)
        acc[j] = __builtin_amdgcn_mfma_f32_16x16x32_f16(a0, b0[j], acc[j], 0, 0, 0);
      #pragma unroll
      for (int j = 0; j < 8; ++j)
        acc[j] = __builtin_amdgcn_mfma_f32_16x16x32_f16(a1, b1[j], acc[j], 0, 0, 0);
      #pragma unroll
      for (int j = 0; j < 8; ++j)
        #pragma unroll
        for (int r = 0; r < 4; ++r)
          h1[(kg*4 + r)*264 + 16*(g*8 + j) + cn] = (_Float16)gelu_f(acc[j][r]);
    }
  }

  // ---- head L2 (K=256, N=64) via MFMA + L3 (64->2) in-register ----
  {
    f32x4 acc[4];
    #pragma unroll
    for (int j = 0; j < 4; ++j) {
      float bv = c2[16*j + cn];
      acc[j] = (f32x4){bv, bv, bv, bv};
    }
    const _Float16* aP  = h1 + cn*264 + kg*8;
    const _Float16* bQ2 = H2P + lane*8;
    half8 bb[4];
    #pragma unroll
    for (int j = 0; j < 4; ++j)
      bb[j] = *reinterpret_cast<const half8*>(bQ2 + j*4096);
    #pragma unroll
    for (int ks = 0; ks < 8; ++ks) {
      half8 a = *reinterpret_cast<const half8*>(aP + ks*32);
      half8 bn[4];
      if (ks < 7) {
        #pragma unroll
        for (int j = 0; j < 4; ++j)
          bn[j] = *reinterpret_cast<const half8*>(bQ2 + j*4096 + (ks+1)*512);
      }
      #pragma unroll
      for (int j = 0; j < 4; ++j)
        acc[j] = __builtin_amdgcn_mfma_f32_16x16x32_f16(a, bb[j], acc[j], 0, 0, 0);
      if (ks < 7) {
        #pragma unroll
        for (int j = 0; j < 4; ++j) bb[j] = bn[j];
      }
    }
    // L3: gelu on acc, dot with H3 per row, 16-lane butterfly, softplus
    float h30[4], h31[4];
    #pragma unroll
    for (int j = 0; j < 4; ++j) {
      h30[j] = H3[(16*j + cn)*2 + 0];
      h31[j] = H3[(16*j + cn)*2 + 1];
    }
    const float c30 = c3[0], c31 = c3[1];
    #pragma unroll
    for (int r = 0; r < 4; ++r) {
      float p0 = 0.f, p1 = 0.f;
      #pragma unroll
      for (int j = 0; j < 4; ++j) {
        float g = gelu_f(acc[j][r]);
        p0 = fmaf(g, h30[j], p0);
        p1 = fmaf(g, h31[j], p1);
      }
      #pragma unroll
      for (int o = 1; o < 16; o <<= 1) {
        p0 += __shfl_xor(p0, o);
        p1 += __shfl_xor(p1, o);
      }
      if (cn == 0 && kg < 2) {            // only rows 0-7 are valid
        int row = row0 + kg*4 + r;
        float m = p0 + c30;
        float sa = p1 + c31;
        float sv = fmaxf(sa, 0.f) + log1pf(__expf(-fabsf(sa)));  // softplus
        outp[(size_t)row*2 + 0] = m;
        outp[(size_t)row*2 + 1] = sv;
      }
    }
  }
}

// ---------------------------------------------------------------------------
extern "C" void kernel_launch(void* const* d_in, const int* in_sizes, int n_in,
                              void* d_out, int out_size, void* d_ws, size_t ws_size,
                              hipStream_t stream) {
  const float* s_ctx  = (const float*)d_in[0];
  const float* f_ctx  = (const float*)d_in[1];
  const float* s_test = (const float*)d_in[2];
  const float* emb    = (const float*)d_in[3];
  const float* W1 = (const float*)d_in[4];
  const float* b1 = (const float*)d_in[5];
  const float* W2 = (const float*)d_in[6];
  const float* b2 = (const float*)d_in[7];
  const float* W3 = (const float*)d_in[8];
  const float* b3 = (const float*)d_in[9];
  const float* ln_g = (const float*)d_in[10];
  const float* ln_b = (const float*)d_in[11];
  const float* Wg = (const float*)d_in[12];
  const float* a_src = (const float*)d_in[13];
  const float* a_dst = (const float*)d_in[14];
  const float* We = (const float*)d_in[15];
  const float* be = (const float*)d_in[16];
  const float* H1 = (const float*)d_in[17];
  const float* c1 = (const float*)d_in[18];
  const float* H2 = (const float*)d_in[19];
  const float* c2 = (const float*)d_in[20];
  const float* H3 = (const float*)d_in[21];
  const float* c3 = (const float*)d_in[22];

  float* nodes   = (float*)d_ws;                       // NTOT x 64 fp32
  _Float16* xph  = (_Float16*)(nodes + (size_t)NTOT*64);  // NTOT x 64 fp16
  int*   senders = (int*)(xph + (size_t)NTOT*64);      // NTEST_TOT x 16
  _Float16* W2P  = (_Float16*)(senders + (size_t)NTEST_TOT*16); // 32768 halves
  _Float16* W3P  = W2P + 32768;                        // 8192 halves
  _Float16* WgP  = W3P + 8192;                         // 4096 halves
  _Float16* H1P  = WgP + 4096;                         // 16384 halves
  _Float16* H2P  = H1P + 16384;                        // 16384 halves
  float*   ctype = (float*)(H2P + 16384);              // [2][256]
  float*   xps   = ctype + 512;                        // NCTX_TOT x 4
  float*   xpd   = xps + (size_t)NCTX_TOT*4;           // NTEST_TOT x 4
  float* outp    = (float*)d_out;

  hipLaunchKernelGGL(prep_kernel, dim3(16), dim3(256), 0, stream,
                     W1, b1, emb, W2, W3, Wg, H1, H2,
                     W2P, W3P, WgP, H1P, H2P, ctype);
  hipLaunchKernelGGL(knn_kernel, dim3(4096), dim3(256), 0, stream,
                     s_ctx, s_test, senders);
  hipLaunchKernelGGL(mlp_kernel, dim3(768), dim3(256), 0, stream,
                     s_ctx, f_ctx, s_test, ctype, W1,
                     W2P, b2, W3P, b3, ln_g, ln_b, WgP,
                     a_src, a_dst, nodes, xph, xps, xpd);
  hipLaunchKernelGGL(back_kernel, dim3(2048), dim3(64), 0, stream,
                     s_ctx, s_test, xph, senders, xps, xpd, We, be,
                     nodes, H1P, c1, H2P, c2, H3, c3, outp);
}

// Round 5
// 71.708 us; speedup vs baseline: 2.1470x; 1.0732x over previous
//
#include <hip/hip_runtime.h>
#include <math.h>

#define NB 16
#define NCTX 2048
#define NTEST 1024
#define NCTX_TOT (NB*NCTX)      /* 32768 */
#define NTEST_TOT (NB*NTEST)    /* 16384 */
#define NTOT (NCTX_TOT + NTEST_TOT) /* 49152 */

typedef _Float16 half8 __attribute__((ext_vector_type(8)));
typedef _Float16 half4 __attribute__((ext_vector_type(4)));
typedef float f32x4 __attribute__((ext_vector_type(4)));

__device__ __forceinline__ float gelu_f(float x) {
  float x3 = x * x * x;
  float y = 0.7978845608028654f * fmaf(0.044715f, x3, x);
  float e = __expf(2.0f * y);
  float th = 1.0f - 2.0f * __builtin_amdgcn_rcpf(e + 1.0f);
  return 0.5f * x * (1.0f + th);
}

__device__ __forceinline__ void fma4(float4& a, float s, float4 w) {
  a.x = fmaf(s, w.x, a.x);
  a.y = fmaf(s, w.y, a.y);
  a.z = fmaf(s, w.z, a.z);
  a.w = fmaf(s, w.w, a.w);
}

__device__ __forceinline__ float4 ldg4(const float* p) {
  return *reinterpret_cast<const float4*>(p);
}

__device__ __forceinline__ unsigned fkey(float f) {
  unsigned u = __float_as_uint(f);
  return (u & 0x80000000u) ? ~u : (u ^ 0x80000000u);
}
__device__ __forceinline__ float unfkey(unsigned k) {
  return (k & 0x80000000u) ? __uint_as_float(k ^ 0x80000000u)
                           : __uint_as_float(~k);
}

// ---------------------------------------------------------------------------
// Fused KNN + weight-prep kernel. Blocks 0..39: prep role, one pack item per
// thread (10240 items; all role boundaries are multiples of 64 -> wave-
// uniform). Blocks 40..4135: knn role (R3-verbatim math). Prep executes in
// the knn's latency shadow; one launch + gap removed. Pack recipe (R10):
// P[((j*KS+ks)*64+l)*8+e] = fp16(W[(ks*32+(l>>4)*8+e)*N + 16j+(l&15)])
// ---------------------------------------------------------------------------
__global__ __launch_bounds__(256, 6) void knn_prep_kernel(
    const float* __restrict__ s_ctx, const float* __restrict__ s_test,
    int* __restrict__ senders,
    const float* __restrict__ W1, const float* __restrict__ b1,
    const float* __restrict__ emb,
    const float* __restrict__ W2, const float* __restrict__ W3,
    const float* __restrict__ Wg,
    const float* __restrict__ H1, const float* __restrict__ H2,
    _Float16* __restrict__ W2P, _Float16* __restrict__ W3P,
    _Float16* __restrict__ WgP,
    _Float16* __restrict__ H1P, _Float16* __restrict__ H2P,
    float* __restrict__ ctype)
{
  __shared__ __align__(16) unsigned long long sk[4][128];   // 4096 B
  const int blk = blockIdx.x;

  if (blk < 40) {
    // ---------------- prep role: one pack item per thread ----------------
    const int t = blk*256 + (int)threadIdx.x;     // 0..10239
    if (t < 4096) {            // W2: N=128, KS=8
      int i = t;
      int j = i >> 9, ks = (i >> 6) & 7, l = i & 63;
      int col = 16*j + (l & 15);
      int k0  = ks*32 + (l >> 4)*8;
      half8 o;
      #pragma unroll
      for (int e = 0; e < 8; ++e) o[e] = (_Float16)W2[(k0 + e)*128 + col];
      *reinterpret_cast<half8*>(&W2P[(size_t)i*8]) = o;
    } else if (t < 5120) {     // W3: N=64, KS=4
      int i = t - 4096;
      int j = i >> 8, ks = (i >> 6) & 3, l = i & 63;
      int col = 16*j + (l & 15);
      int k0  = ks*32 + (l >> 4)*8;
      half8 o;
      #pragma unroll
      for (int e = 0; e < 8; ++e) o[e] = (_Float16)W3[(k0 + e)*64 + col];
      *reinterpret_cast<half8*>(&W3P[(size_t)i*8]) = o;
    } else if (t < 5632) {     // Wg: N=64, KS=2
      int i = t - 5120;
      int j = i >> 7, ks = (i >> 6) & 1, l = i & 63;
      int col = 16*j + (l & 15);
      int k0  = ks*32 + (l >> 4)*8;
      half8 o;
      #pragma unroll
      for (int e = 0; e < 8; ++e) o[e] = (_Float16)Wg[(k0 + e)*64 + col];
      *reinterpret_cast<half8*>(&WgP[(size_t)i*8]) = o;
    } else if (t < 7680) {     // H1: N=256, KS=2
      int i = t - 5632;
      int j = i >> 7, ks = (i >> 6) & 1, l = i & 63;
      int col = 16*j + (l & 15);
      int k0  = ks*32 + (l >> 4)*8;
      half8 o;
      #pragma unroll
      for (int e = 0; e < 8; ++e) o[e] = (_Float16)H1[(k0 + e)*256 + col];
      *reinterpret_cast<half8*>(&H1P[(size_t)i*8]) = o;
    } else if (t < 9728) {     // H2: N=64, KS=8
      int i = t - 7680;
      int j = i >> 9, ks = (i >> 6) & 7, l = i & 63;
      int col = 16*j + (l & 15);
      int k0  = ks*32 + (l >> 4)*8;
      half8 o;
      #pragma unroll
      for (int e = 0; e < 8; ++e) o[e] = (_Float16)H2[(k0 + e)*64 + col];
      *reinterpret_cast<half8*>(&H2P[(size_t)i*8]) = o;
    } else {                   // ctype [2][256]
      int i = t - 9728;        // 0..511
      int ty = i >> 8, c = i & 255;
      float acc = b1[c];
      #pragma unroll
      for (int k = 0; k < 4; ++k) acc = fmaf(emb[ty*4 + k], W1[k*256 + c], acc);
      ctype[i] = acc;
    }
    return;
  }

  // ---------------- knn role (R3 verbatim math) ---------------------------
  const int t    = threadIdx.x;
  const int lane = t & 63;
  const int w    = t >> 6;                       // 0..3
  const int blk2 = blk - 40;                     // 0..4095
  const int bb   = blk2 >> 8;                    // batch
  const int q    = (blk2 & 255) * 4 + w;         // 0..1023
  const int trow = bb * NTEST + q;

  const float* cb = s_ctx + (size_t)bb * NCTX * 2;
  const float qx = s_test[(size_t)trow*2];
  const float qy = s_test[(size_t)trow*2 + 1];
  const float qq = __fadd_rn(__fmul_rn(qx,qx), __fmul_rn(qy,qy));

  float d[32];
  float mn = 3.4e38f;
  #pragma unroll
  for (int it = 0; it < 32; ++it) {
    float2 p = *reinterpret_cast<const float2*>(&cb[2*(it*64 + lane)]);
    float ss  = __fadd_rn(__fmul_rn(p.x,p.x), __fmul_rn(p.y,p.y));
    float dot = __fadd_rn(__fmul_rn(qx, p.x), __fmul_rn(qy, p.y));
    float d2  = __fsub_rn(__fadd_rn(qq, ss), __fmul_rn(2.0f, dot));
    d[it] = d2;
    mn = fminf(mn, d2);
  }

  unsigned key = fkey(mn);
  unsigned acc = 0u;
  #pragma unroll
  for (int bit = 31; bit >= 0; --bit) {
    unsigned candv = acc | (1u << bit);
    unsigned long long bal = __ballot(key < candv);
    if (__popcll(bal) < 16) acc = candv;
  }
  const float Tf = unfkey(acc);

  int base = 0;
  #pragma unroll
  for (int it = 0; it < 32; ++it) {
    bool pr = (d[it] <= Tf);
    unsigned long long m = __ballot(pr);
    if (pr) {
      int pos = base + __popcll(m & ((1ULL << lane) - 1ULL));
      if (pos < 128)
        sk[w][pos] = ((unsigned long long)fkey(d[it]) << 32)
                   | (unsigned)(it*64 + lane);       // idx in [0,2047]
    }
    base += __popcll(m);
  }
  const int S = base;                   // uniform; S >= 16 guaranteed

  if (S <= 32) {
    // pad remaining slots so the unrolled compare is safe
    if (lane >= S && lane < 32) sk[w][lane] = ~0ULL;
    unsigned long long pm = sk[w][lane & 31];
    int r0 = 0;
    #pragma unroll
    for (int j = 0; j < 32; ++j)
      r0 += (int)(sk[w][j] < pm);       // (key,idx) lexicographic rank
    if (lane < S && r0 < 16)
      senders[(size_t)trow*16 + r0] = bb*NCTX + (int)(pm & 0xFFFFFFFFu);
  } else if (S <= 128) {
    unsigned long long p0 = (lane      < S) ? sk[w][lane]      : ~0ULL;
    unsigned long long p1 = (lane + 64 < S) ? sk[w][lane + 64] : ~0ULL;
    int r0 = 0, r1 = 0;
    for (int j = 0; j < S; ++j) {       // broadcast LDS reads
      unsigned long long kj = sk[w][j];
      r0 += (int)(kj < p0);
      r1 += (int)(kj < p1);
    }
    if (lane < S && r0 < 16)
      senders[(size_t)trow*16 + r0] = bb*NCTX + (int)(p0 & 0xFFFFFFFFu);
    if (lane + 64 < S && r1 < 16)
      senders[(size_t)trow*16 + r1] = bb*NCTX + (int)(p1 & 0xFFFFFFFFu);
  } else {
    if (lane == 0) {
      float dist[16]; int ind[16];
      #pragma unroll
      for (int j=0;j<16;++j){ dist[j]=3.4e38f; ind[j]=0; }
      for (int c = 0; c < NCTX; ++c) {
        float2 p = *reinterpret_cast<const float2*>(&cb[2*c]);
        float ss  = __fadd_rn(__fmul_rn(p.x,p.x), __fmul_rn(p.y,p.y));
        float dot = __fadd_rn(__fmul_rn(qx, p.x), __fmul_rn(qy, p.y));
        float d2  = __fsub_rn(__fadd_rn(qq, ss), __fmul_rn(2.0f, dot));
        if (d2 < dist[15]) {
          float dj = d2; int ij = c;
          #pragma unroll
          for (int j = 0; j < 16; ++j) {
            bool sw = dj < dist[j];
            float td = dist[j]; int ti = ind[j];
            dist[j] = sw ? dj : td;  ind[j] = sw ? ij : ti;
            dj = sw ? td : dj;       ij = sw ? ti : ij;
          }
        }
      }
      for (int j = 0; j < 16; ++j)
        senders[(size_t)trow*16 + j] = bb*NCTX + ind[j];
    }
  }
}

// ---------------------------------------------------------------------------
// node_mlp kernel (R1 verbatim, known-good). grid 768 x 256, each wave owns
// one 16-row tile. LDS 34816; (256,4).
// ---------------------------------------------------------------------------
__global__ __launch_bounds__(256, 4) void mlp_kernel(
    const float* __restrict__ s_ctx, const float* __restrict__ f_ctx,
    const float* __restrict__ s_test,
    const float* __restrict__ ctype, const float* __restrict__ W1,
    const _Float16* __restrict__ W2P, const float* __restrict__ b2,
    const _Float16* __restrict__ W3P, const float* __restrict__ b3,
    const float* __restrict__ ln_g, const float* __restrict__ ln_b,
    const _Float16* __restrict__ WgP,
    const float* __restrict__ a_src, const float* __restrict__ a_dst,
    float* __restrict__ nodes, _Float16* __restrict__ xph,
    float* __restrict__ xps, float* __restrict__ xpd)
{
  __shared__ __align__(16) char smem[34816];
  const int t    = threadIdx.x;
  const int lane = t & 63;
  const int w    = t >> 6;
  const int id   = blockIdx.x;        // 0..767
  char* slice = smem + w * 8704;
  _Float16* h1t  = reinterpret_cast<_Float16*>(slice);     // [16][264]
  float (*xin)[4] = reinterpret_cast<float(*)[4]>(slice + 8448);
  _Float16* h2   = h1t;               // overlay after h1 consumed
  _Float16* nodh = h1t + 16*136;
  const int cn = lane & 15;
  const int kg = lane >> 4;
  const int m0 = (id*4 + w) * 16;
  const bool is_ctx = (m0 < NCTX_TOT);   // uniform per wave

  const _Float16* bQ2 = W2P + lane*8;
  const _Float16* bQ3 = W3P + lane*8;
  const _Float16* bQg = WgP + lane*8;

  half8 bb2[8];
  #pragma unroll
  for (int j = 0; j < 8; ++j)
    bb2[j] = *reinterpret_cast<const half8*>(bQ2 + j*4096);

  { // stage per-row inputs
    int r = lane >> 2, c = lane & 3;
    int n = m0 + r;
    float v;
    if (is_ctx) v = (c < 2) ? s_ctx[2*(size_t)n + c] : f_ctx[2*(size_t)n + (c-2)];
    else { int tn = n - NCTX_TOT; v = (c < 2) ? s_test[2*(size_t)tn + c] : 0.f; }
    xin[r][c] = v;
  }

  { // L1
    const int c0 = lane * 4;
    float4 w4 = ldg4(&W1[4*256 + c0]);
    float4 w5 = ldg4(&W1[5*256 + c0]);
    float4 w6 = ldg4(&W1[6*256 + c0]);
    float4 w7 = ldg4(&W1[7*256 + c0]);
    float4 cbv = ldg4(&ctype[(is_ctx ? 256 : 0) + c0]);
    #pragma unroll
    for (int r = 0; r < 16; ++r) {
      float4 xi = *reinterpret_cast<const float4*>(&xin[r][0]);
      float4 a = cbv;
      fma4(a, xi.x, w4); fma4(a, xi.y, w5);
      fma4(a, xi.z, w6); fma4(a, xi.w, w7);
      half4 o = { (_Float16)gelu_f(a.x), (_Float16)gelu_f(a.y),
                  (_Float16)gelu_f(a.z), (_Float16)gelu_f(a.w) };
      *reinterpret_cast<half4*>(&h1t[r*264 + c0]) = o;
    }
  }

  { // L2
    f32x4 acc[8];
    #pragma unroll
    for (int j = 0; j < 8; ++j) {
      float bv = b2[16*j + cn];
      acc[j] = (f32x4){bv, bv, bv, bv};
    }
    const _Float16* aP = h1t + cn*264 + kg*8;
    #pragma unroll
    for (int ks = 0; ks < 8; ++ks) {
      half8 a = *reinterpret_cast<const half8*>(aP + ks*32);
      half8 bn[8];
      if (ks < 7) {
        #pragma unroll
        for (int j = 0; j < 8; ++j)
          bn[j] = *reinterpret_cast<const half8*>(bQ2 + j*4096 + (ks+1)*512);
      }
      #pragma unroll
      for (int j = 0; j < 8; ++j)
        acc[j] = __builtin_amdgcn_mfma_f32_16x16x32_f16(a, bb2[j], acc[j], 0, 0, 0);
      if (ks < 7) {
        #pragma unroll
        for (int j = 0; j < 8; ++j) bb2[j] = bn[j];
      }
    }
    #pragma unroll
    for (int j = 0; j < 8; ++j)
      #pragma unroll
      for (int r = 0; r < 4; ++r) {
        int m = kg*4 + r;
        h2[m*136 + 16*j + cn] = (_Float16)gelu_f(acc[j][r]);
      }
  }

  { // L3 + LN
    f32x4 acc[4];
    #pragma unroll
    for (int j = 0; j < 4; ++j) {
      float bv = b3[16*j + cn];
      acc[j] = (f32x4){bv, bv, bv, bv};
    }
    const _Float16* aP = h2 + cn*136 + kg*8;
    half8 bb[4];
    #pragma unroll
    for (int j = 0; j < 4; ++j)
      bb[j] = *reinterpret_cast<const half8*>(bQ3 + j*2048);
    #pragma unroll
    for (int ks = 0; ks < 4; ++ks) {
      half8 a = *reinterpret_cast<const half8*>(aP + ks*32);
      half8 bn[4];
      if (ks < 3) {
        #pragma unroll
        for (int j = 0; j < 4; ++j)
          bn[j] = *reinterpret_cast<const half8*>(bQ3 + j*2048 + (ks+1)*512);
      }
      #pragma unroll
      for (int j = 0; j < 4; ++j)
        acc[j] = __builtin_amdgcn_mfma_f32_16x16x32_f16(a, bb[j], acc[j], 0, 0, 0);
      if (ks < 3) {
        #pragma unroll
        for (int j = 0; j < 4; ++j) bb[j] = bn[j];
      }
    }
    float gv[4], bvv[4];
    #pragma unroll
    for (int j = 0; j < 4; ++j) { gv[j] = ln_g[16*j+cn]; bvv[j] = ln_b[16*j+cn]; }
    const bool is_test = !is_ctx;
    #pragma unroll
    for (int r = 0; r < 4; ++r) {
      float sv = 0.f, sq = 0.f;
      #pragma unroll
      for (int j = 0; j < 4; ++j) {
        float v = acc[j][r];
        sv += v; sq += v*v;
      }
      #pragma unroll
      for (int o = 1; o < 16; o <<= 1) {
        sv += __shfl_xor(sv, o);
        sq += __shfl_xor(sq, o);
      }
      float mean = sv * (1.0f/64.0f);
      float var  = sq * (1.0f/64.0f) - mean*mean;
      float rstd = rsqrtf(var + 1e-6f);
      int m = kg*4 + r;
      #pragma unroll
      for (int j = 0; j < 4; ++j) {
        float v = (acc[j][r] - mean) * rstd * gv[j] + bvv[j];
        nodh[m*72 + 16*j + cn] = (_Float16)v;
        if (is_test)
          nodes[(size_t)(m0 + m)*64 + 16*j + cn] = v;
      }
    }
  }

  { // xp(@fp16) = LN @ Wg, plus per-head xps/xpd emission
    f32x4 acc[4];
    #pragma unroll
    for (int j = 0; j < 4; ++j) acc[j] = (f32x4){0.f, 0.f, 0.f, 0.f};
    const _Float16* aP = nodh + cn*72 + kg*8;
    half8 bg0[4], bg1[4];
    #pragma unroll
    for (int j = 0; j < 4; ++j) {
      bg0[j] = *reinterpret_cast<const half8*>(bQg + j*1024);
      bg1[j] = *reinterpret_cast<const half8*>(bQg + j*1024 + 512);
    }
    half8 a0 = *reinterpret_cast<const half8*>(aP);
    half8 a1 = *reinterpret_cast<const half8*>(aP + 32);
    #pragma unroll
    for (int j = 0; j < 4; ++j)
      acc[j] = __builtin_amdgcn_mfma_f32_16x16x32_f16(a0, bg0[j], acc[j], 0, 0, 0);
    #pragma unroll
    for (int j = 0; j < 4; ++j)
      acc[j] = __builtin_amdgcn_mfma_f32_16x16x32_f16(a1, bg1[j], acc[j], 0, 0, 0);
    #pragma unroll
    for (int r = 0; r < 4; ++r) {
      int m = kg*4 + r;
      #pragma unroll
      for (int j = 0; j < 4; ++j)
        xph[(size_t)(m0 + m)*64 + 16*j + cn] = (_Float16)acc[j][r];
    }
    const float* av = is_ctx ? a_src : a_dst;
    float av0 = av[cn], av1 = av[16+cn], av2 = av[32+cn], av3 = av[48+cn];
    #pragma unroll
    for (int r = 0; r < 4; ++r) {
      float p0 = acc[0][r]*av0, p1 = acc[1][r]*av1;
      float p2 = acc[2][r]*av2, p3 = acc[3][r]*av3;
      #pragma unroll
      for (int o = 1; o < 16; o <<= 1) {
        p0 += __shfl_xor(p0, o); p1 += __shfl_xor(p1, o);
        p2 += __shfl_xor(p2, o); p3 += __shfl_xor(p3, o);
      }
      if (cn == 0) {
        int m = kg*4 + r;
        float4 v = make_float4(p0, p1, p2, p3);
        if (is_ctx)
          *reinterpret_cast<float4*>(&xps[(size_t)(m0 + m)*4]) = v;
        else
          *reinterpret_cast<float4*>(&xpd[(size_t)(m0 + m - NCTX_TOT)*4]) = v;
      }
    }
  }
}

// ---------------------------------------------------------------------------
// Back kernel (R4 verbatim): 8 test rows per wave, grid 2048, 8 waves/CU.
// MFMA tiles stay 16x16 with A rows 8-15 zero-filled; write-guarded.
// ---------------------------------------------------------------------------
__global__ __launch_bounds__(64, 3) void back_kernel(
    const float* __restrict__ s_ctx, const float* __restrict__ s_test,
    const _Float16* __restrict__ xph, const int* __restrict__ senders,
    const float* __restrict__ xps, const float* __restrict__ xpd,
    const float* __restrict__ We, const float* __restrict__ be,
    const float* __restrict__ nodes,
    const _Float16* __restrict__ H1P, const float* __restrict__ c1,
    const _Float16* __restrict__ H2P, const float* __restrict__ c2,
    const float* __restrict__ H3, const float* __restrict__ c3,
    float* __restrict__ outp)
{
  __shared__ __align__(16) _Float16 xinh[16*72];   // 2304 B (rows 8-15 zeroed)
  __shared__ __align__(16) _Float16 h1[16*264];    // 8448 B
  const int lane = threadIdx.x;       // one wave
  const int cn   = lane & 15;
  const int kg   = lane >> 4;
  const int bid  = blockIdx.x;                    // 2048
  const int L    = (bid & 7)*256 + (bid >> 3);    // XCD-contiguous
  const int row0 = L * 8;                         // test-local row base

  // zero A rows 8-15 (single wave: program order suffices, no barrier)
  #pragma unroll
  for (int rr = 8; rr < 16; ++rr) xinh[rr*72 + lane] = (_Float16)0.f;

  { // ---- attn: 8 rows, score layout lane=(h,kk), h==kg ----
    const int h  = kg;
    const int kk = cn;
    const int hb = lane & 48;
    const float we0 = We[h], we1 = We[4+h], beh = be[h];
    for (int rr = 0; rr < 8; ++rr) {
      const int trow = row0 + rr;
      int s = senders[(size_t)trow*16 + kk];
      s = (s < 0) ? 0 : ((s >= NCTX_TOT) ? NCTX_TOT - 1 : s);  // safety clamp
      float pre = xps[(size_t)s*4 + h] + xpd[(size_t)trow*4 + h];
      float lr  = pre >= 0.f ? pre : 0.2f * pre;
      const float qx = s_test[(size_t)trow*2];
      const float qy = s_test[(size_t)trow*2 + 1];
      float ex = qx - s_ctx[(size_t)s*2];
      float ey = qy - s_ctx[(size_t)s*2 + 1];
      float sc = lr + fmaf(ex, we0, fmaf(ey, we1, beh));
      float mx = sc;
      #pragma unroll
      for (int o = 1; o < 16; o <<= 1) mx = fmaxf(mx, __shfl_xor(mx, o));
      float e = __expf(sc - mx);
      float sum = e;
      #pragma unroll
      for (int o = 1; o < 16; o <<= 1) sum += __shfl_xor(sum, o);
      float alpha = e / sum;
      // PV: lane = h*16+d reads alphas of its head via in-group shfl
      float outv = 0.f;
      #pragma unroll
      for (int k = 0; k < 16; ++k) {
        int   sk = __shfl(s, k);            // same across head groups
        float al = __shfl(alpha, hb + k);
        outv = fmaf(al, (float)xph[(size_t)sk*64 + lane], outv);
      }
      float xv = nodes[(size_t)(NCTX_TOT + trow)*64 + lane] + outv;
      xinh[rr*72 + lane] = (_Float16)xv;
    }
  }

  // ---- head L1 (K=64, N=256) via MFMA, two groups of 8 N-tiles ----
  {
    const _Float16* aP  = xinh + cn*72 + kg*8;
    const _Float16* bQ1 = H1P + lane*8;
    half8 a0 = *reinterpret_cast<const half8*>(aP);
    half8 a1 = *reinterpret_cast<const half8*>(aP + 32);
    #pragma unroll
    for (int g = 0; g < 2; ++g) {
      f32x4 acc[8];
      #pragma unroll
      for (int j = 0; j < 8; ++j) {
        float bv = c1[16*(g*8 + j) + cn];
        acc[j] = (f32x4){bv, bv, bv, bv};
      }
      half8 b0[8], b1[8];
      #pragma unroll
      for (int j = 0; j < 8; ++j) {
        b0[j] = *reinterpret_cast<const half8*>(bQ1 + ((g*8 + j)*2 + 0)*512);
        b1[j] = *reinterpret_cast<const half8*>(bQ1 + ((g*8 + j)*2 + 1)*512);
      }
      #pragma unroll
      for (int j = 0; j < 8; ++j)
        acc[j] = __builtin_amdgcn_mfma_f32_16x16x32_f16(a0, b0[j], acc[j], 0, 0, 0);
      #pragma unroll
      for (int j = 0; j < 8; ++j)
        acc[j] = __builtin_amdgcn_mfma_f32_16x16x32_f16(a1, b1[j], acc[j], 0, 0, 0);
      #pragma unroll
      for (int j = 0; j < 8; ++j)
        #pragma unroll
        for (int r = 0; r < 4; ++r)
          h1[(kg*4 + r)*264 + 16*(g*8 + j) + cn] = (_Float16)gelu_f(acc[j][r]);
    }
  }

  // ---- head L2 (K=256, N=64) via MFMA + L3 (64->2) in-register ----
  {
    f32x4 acc[4];
    #pragma unroll
    for (int j = 0; j < 4; ++j) {
      float bv = c2[16*j + cn];
      acc[j] = (f32x4){bv, bv, bv, bv};
    }
    const _Float16* aP  = h1 + cn*264 + kg*8;
    const _Float16* bQ2 = H2P + lane*8;
    half8 bb[4];
    #pragma unroll
    for (int j = 0; j < 4; ++j)
      bb[j] = *reinterpret_cast<const half8*>(bQ2 + j*4096);
    #pragma unroll
    for (int ks = 0; ks < 8; ++ks) {
      half8 a = *reinterpret_cast<const half8*>(aP + ks*32);
      half8 bn[4];
      if (ks < 7) {
        #pragma unroll
        for (int j = 0; j < 4; ++j)
          bn[j] = *reinterpret_cast<const half8*>(bQ2 + j*4096 + (ks+1)*512);
      }
      #pragma unroll
      for (int j = 0; j < 4; ++j)
        acc[j] = __builtin_amdgcn_mfma_f32_16x16x32_f16(a, bb[j], acc[j], 0, 0, 0);
      if (ks < 7) {
        #pragma unroll
        for (int j = 0; j < 4; ++j) bb[j] = bn[j];
      }
    }
    // L3: gelu on acc, dot with H3 per row, 16-lane butterfly, softplus
    float h30[4], h31[4];
    #pragma unroll
    for (int j = 0; j < 4; ++j) {
      h30[j] = H3[(16*j + cn)*2 + 0];
      h31[j] = H3[(16*j + cn)*2 + 1];
    }
    const float c30 = c3[0], c31 = c3[1];
    #pragma unroll
    for (int r = 0; r < 4; ++r) {
      float p0 = 0.f, p1 = 0.f;
      #pragma unroll
      for (int j = 0; j < 4; ++j) {
        float g = gelu_f(acc[j][r]);
        p0 = fmaf(g, h30[j], p0);
        p1 = fmaf(g, h31[j], p1);
      }
      #pragma unroll
      for (int o = 1; o < 16; o <<= 1) {
        p0 += __shfl_xor(p0, o);
        p1 += __shfl_xor(p1, o);
      }
      if (cn == 0 && kg < 2) {            // only rows 0-7 are valid
        int row = row0 + kg*4 + r;
        float m = p0 + c30;
        float sa = p1 + c31;
        float sv = fmaxf(sa, 0.f) + log1pf(__expf(-fabsf(sa)));  // softplus
        outp[(size_t)row*2 + 0] = m;
        outp[(size_t)row*2 + 1] = sv;
      }
    }
  }
}

// ---------------------------------------------------------------------------
extern "C" void kernel_launch(void* const* d_in, const int* in_sizes, int n_in,
                              void* d_out, int out_size, void* d_ws, size_t ws_size,
                              hipStream_t stream) {
  const float* s_ctx  = (const float*)d_in[0];
  const float* f_ctx  = (const float*)d_in[1];
  const float* s_test = (const float*)d_in[2];
  const float* emb    = (const float*)d_in[3];
  const float* W1 = (const float*)d_in[4];
  const float* b1 = (const float*)d_in[5];
  const float* W2 = (const float*)d_in[6];
  const float* b2 = (const float*)d_in[7];
  const float* W3 = (const float*)d_in[8];
  const float* b3 = (const float*)d_in[9];
  const float* ln_g = (const float*)d_in[10];
  const float* ln_b = (const float*)d_in[11];
  const float* Wg = (const float*)d_in[12];
  const float* a_src = (const float*)d_in[13];
  const float* a_dst = (const float*)d_in[14];
  const float* We = (const float*)d_in[15];
  const float* be = (const float*)d_in[16];
  const float* H1 = (const float*)d_in[17];
  const float* c1 = (const float*)d_in[18];
  const float* H2 = (const float*)d_in[19];
  const float* c2 = (const float*)d_in[20];
  const float* H3 = (const float*)d_in[21];
  const float* c3 = (const float*)d_in[22];

  float* nodes   = (float*)d_ws;                       // NTOT x 64 fp32
  _Float16* xph  = (_Float16*)(nodes + (size_t)NTOT*64);  // NTOT x 64 fp16
  int*   senders = (int*)(xph + (size_t)NTOT*64);      // NTEST_TOT x 16
  _Float16* W2P  = (_Float16*)(senders + (size_t)NTEST_TOT*16); // 32768 halves
  _Float16* W3P  = W2P + 32768;                        // 8192 halves
  _Float16* WgP  = W3P + 8192;                         // 4096 halves
  _Float16* H1P  = WgP + 4096;                         // 16384 halves
  _Float16* H2P  = H1P + 16384;                        // 16384 halves
  float*   ctype = (float*)(H2P + 16384);              // [2][256]
  float*   xps   = ctype + 512;                        // NCTX_TOT x 4
  float*   xpd   = xps + (size_t)NCTX_TOT*4;           // NTEST_TOT x 4
  float* outp    = (float*)d_out;

  hipLaunchKernelGGL(knn_prep_kernel, dim3(4136), dim3(256), 0, stream,
                     s_ctx, s_test, senders,
                     W1, b1, emb, W2, W3, Wg, H1, H2,
                     W2P, W3P, WgP, H1P, H2P, ctype);
  hipLaunchKernelGGL(mlp_kernel, dim3(768), dim3(256), 0, stream,
                     s_ctx, f_ctx, s_test, ctype, W1,
                     W2P, b2, W3P, b3, ln_g, ln_b, WgP,
                     a_src, a_dst, nodes, xph, xps, xpd);
  hipLaunchKernelGGL(back_kernel, dim3(2048), dim3(64), 0, stream,
                     s_ctx, s_test, xph, senders, xps, xpd, We, be,
                     nodes, H1P, c1, H2P, c2, H3, c3, outp);
}